// Round 1
// baseline (359.907 us; speedup 1.0000x reference)
//
#include <hip/hip_runtime.h>

// Pipeline: [T1] w_qkv -> wqkvT (bf16)   [T2] w_out -> woutT (bf16)
//           [G1] qkv = x @ w_qkv  (f32 A cast in staging, bf16 out, M=8192 N=3072 K=1024)
//           [A ] flash attention w/ relative-position bias -> attnb (bf16)
//           [G3] out = attnb @ w_out (f32 out, M=8192 N=1024 K=1024)
// ws layout: wqkvT @0 (6MB) | woutT @6MB (2MB) | qkv @8MB (48MB) | attnb @56MB (16MB) = 72MB

typedef __attribute__((ext_vector_type(8))) short bf16x8;
typedef __attribute__((ext_vector_type(4))) float f32x4;
typedef unsigned short u16;
typedef unsigned int u32;

__device__ __forceinline__ u16 f2bf(float f) {
  u32 u = __builtin_bit_cast(u32, f);
  u = (u + 0x7fffu + ((u >> 16) & 1u)) >> 16;
  return (u16)u;
}

__device__ __forceinline__ f32x4 mfma16(bf16x8 a, bf16x8 b, f32x4 c) {
  return __builtin_amdgcn_mfma_f32_16x16x32_bf16(a, b, c, 0, 0, 0);
}

// ---------------- transpose + cast: in[R][C] f32 -> out[C][R] bf16 ----------------
__global__ __launch_bounds__(256) void transpose_cast_kernel(const float* __restrict__ in,
                                                             u16* __restrict__ out,
                                                             int R, int C) {
  __shared__ float tile[32][33];
  const int c0 = blockIdx.x * 32, r0 = blockIdx.y * 32;
  const int tx = threadIdx.x, ty = threadIdx.y;  // 32 x 8
#pragma unroll
  for (int i = 0; i < 32; i += 8)
    tile[ty + i][tx] = in[(size_t)(r0 + ty + i) * C + (c0 + tx)];
  __syncthreads();
#pragma unroll
  for (int i = 0; i < 32; i += 8)
    out[(size_t)(c0 + ty + i) * R + (r0 + tx)] = f2bf(tile[tx][ty + i]);
}

// ---------------- GEMM: C[M][N] = A[M][K] @ BT[N][K]^T ----------------
// 128x128 tile, BK=64, 256 threads (2x2 waves, each 64x64 = 4x4 fragments).
// LDS rows padded to 72 shorts (144B): frag reads 16B-aligned, 2-way conflicts only.
#define GPAD 72

template <bool A_F32, bool OUT_F32>
__global__ __launch_bounds__(256) void gemm_kernel(const void* __restrict__ Ap,
                                                   const u16* __restrict__ BT,
                                                   void* __restrict__ Cp,
                                                   int M, int N, int K) {
  __shared__ u16 As[128][GPAD];
  __shared__ u16 Bs[128][GPAD];
  const int tid = threadIdx.x;
  const int lane = tid & 63, w = tid >> 6;
  const int wrow = w >> 1, wcol = w & 1;
  const int bm0 = blockIdx.y * 128, bn0 = blockIdx.x * 128;
  const int l15 = lane & 15, l4 = lane >> 4;

  const f32x4 zero = {0.f, 0.f, 0.f, 0.f};
  f32x4 acc[4][4];
  for (int i = 0; i < 4; ++i)
    for (int j = 0; j < 4; ++j) acc[i][j] = zero;

  for (int k0 = 0; k0 < K; k0 += 64) {
    __syncthreads();
    if constexpr (A_F32) {
      const float* A = (const float*)Ap;
#pragma unroll
      for (int p = 0; p < 8; ++p) {
        int r = p * 16 + (tid >> 4);
        int c = (tid & 15) * 4;
        float4 v = *(const float4*)(A + (size_t)(bm0 + r) * K + k0 + c);
        uint2 hv;
        hv.x = (u32)f2bf(v.x) | ((u32)f2bf(v.y) << 16);
        hv.y = (u32)f2bf(v.z) | ((u32)f2bf(v.w) << 16);
        *(uint2*)&As[r][c] = hv;
      }
    } else {
      const u16* A = (const u16*)Ap;
#pragma unroll
      for (int p = 0; p < 4; ++p) {
        int r = p * 32 + (tid >> 3);
        int c = (tid & 7) * 8;
        *(uint4*)&As[r][c] = *(const uint4*)(A + (size_t)(bm0 + r) * K + k0 + c);
      }
    }
#pragma unroll
    for (int p = 0; p < 4; ++p) {
      int r = p * 32 + (tid >> 3);
      int c = (tid & 7) * 8;
      *(uint4*)&Bs[r][c] = *(const uint4*)(BT + (size_t)(bn0 + r) * K + k0 + c);
    }
    __syncthreads();
#pragma unroll
    for (int ks = 0; ks < 2; ++ks) {
      bf16x8 afr[4], bfr[4];
#pragma unroll
      for (int mi = 0; mi < 4; ++mi)
        afr[mi] = *(const bf16x8*)&As[wrow * 64 + mi * 16 + l15][ks * 32 + l4 * 8];
#pragma unroll
      for (int ni = 0; ni < 4; ++ni)
        bfr[ni] = *(const bf16x8*)&Bs[wcol * 64 + ni * 16 + l15][ks * 32 + l4 * 8];
#pragma unroll
      for (int mi = 0; mi < 4; ++mi)
#pragma unroll
        for (int ni = 0; ni < 4; ++ni)
          acc[mi][ni] = mfma16(afr[mi], bfr[ni], acc[mi][ni]);
    }
  }

  const int rbase = bm0 + wrow * 64 + l4 * 4;
  const int cbase = bn0 + wcol * 64 + l15;
  if constexpr (OUT_F32) {
    float* C = (float*)Cp;
#pragma unroll
    for (int mi = 0; mi < 4; ++mi)
#pragma unroll
      for (int reg = 0; reg < 4; ++reg)
#pragma unroll
        for (int ni = 0; ni < 4; ++ni)
          C[(size_t)(rbase + mi * 16 + reg) * N + cbase + ni * 16] = acc[mi][ni][reg];
  } else {
    u16* C = (u16*)Cp;
#pragma unroll
    for (int mi = 0; mi < 4; ++mi)
#pragma unroll
      for (int reg = 0; reg < 4; ++reg)
#pragma unroll
        for (int ni = 0; ni < 4; ++ni)
          C[(size_t)(rbase + mi * 16 + reg) * N + cbase + ni * 16] = f2bf(acc[mi][ni][reg]);
  }
}

// ---------------- flash attention with relative position bias ----------------
// qkv[8192][3072] bf16: row b*1024+l, cols h*192 + {0..63 q | 64..127 k | 128..191 v}
// grid (16 q-tiles, 128 b*h), 256 threads = 4 waves x 16 q-rows. KVBLK = 64.
__global__ __launch_bounds__(256) void attn_kernel(const u16* __restrict__ qkv,
                                                   const float* __restrict__ rpe,
                                                   u16* __restrict__ attn_out) {
  __shared__ u16 Ks[64][GPAD];        // K tile  [kv][d]
  __shared__ u16 Vs[64][GPAD];        // V^T     [d][kv]
  __shared__ u16 Ps[4][16][GPAD];     // per-wave P [q][kv]
  __shared__ float rpe_s[1087];       // rpe column h, indices q0 .. q0+1086

  const int tid = threadIdx.x, lane = tid & 63, w = tid >> 6;
  const int l15 = lane & 15, l4 = lane >> 4;
  const int bh = blockIdx.y, h = bh & 15, b = bh >> 4;
  const int q0 = blockIdx.x * 64;

  for (int t = tid; t < 1087; t += 256)
    rpe_s[t] = rpe[(size_t)(q0 + t) * 16 + h];

  // Q fragments held in registers (A row = lane&15, 8 contiguous d at l4*8)
  const u16* qbase = qkv + ((size_t)(b * 1024 + q0 + w * 16) * 3072 + h * 192);
  bf16x8 aq[2];
#pragma unroll
  for (int ks = 0; ks < 2; ++ks)
    aq[ks] = *(const bf16x8*)(qbase + (size_t)l15 * 3072 + ks * 32 + l4 * 8);

  const f32x4 zero = {0.f, 0.f, 0.f, 0.f};
  float m_run[4], l_run[4];
  f32x4 oacc[4];
#pragma unroll
  for (int i = 0; i < 4; ++i) { m_run[i] = -1e30f; l_run[i] = 0.f; oacc[i] = zero; }

  const u16* kvbase = qkv + ((size_t)(b * 1024) * 3072 + h * 192);

  for (int kt = 0; kt < 16; ++kt) {
    const int kv0 = kt * 64;
    __syncthreads();
    // stage K [64][64] row-major
#pragma unroll
    for (int p = 0; p < 2; ++p) {
      int r = tid >> 2;
      int c = (p * 4 + (tid & 3)) * 8;
      *(uint4*)&Ks[r][c] = *(const uint4*)(kvbase + (size_t)(kv0 + r) * 3072 + 64 + c);
    }
    // stage V transposed -> Vs[d][kv]
#pragma unroll
    for (int p = 0; p < 2; ++p) {
      int r = tid >> 2;
      int c = (p * 4 + (tid & 3)) * 8;
      uint4 v = *(const uint4*)(kvbase + (size_t)(kv0 + r) * 3072 + 128 + c);
      const u16* pv = (const u16*)&v;
#pragma unroll
      for (int i = 0; i < 8; ++i) Vs[c + i][r] = pv[i];
    }
    __syncthreads();

    // S = Q K^T  (B-fragment = K rows, contiguous d — no transpose needed)
    f32x4 s[4];
#pragma unroll
    for (int jt = 0; jt < 4; ++jt) {
      f32x4 t = zero;
#pragma unroll
      for (int ks = 0; ks < 2; ++ks) {
        bf16x8 bk = *(const bf16x8*)&Ks[jt * 16 + l15][ks * 32 + l4 * 8];
        t = mfma16(aq[ks], bk, t);
      }
      s[jt] = t;
    }
    // scale + relative position bias: bias(i,j) = rpe[i-j+1023], i=q0+qr, j=kv0+jc
#pragma unroll
    for (int jt = 0; jt < 4; ++jt)
#pragma unroll
      for (int reg = 0; reg < 4; ++reg) {
        int idx = (w * 16 + l4 * 4 + reg) - (kv0 + jt * 16 + l15) + 1023;
        s[jt][reg] = s[jt][reg] * 0.125f + rpe_s[idx];
      }
    // online softmax, rows owned as (l4*4+reg), reduce across lanes 0..15 of group
#pragma unroll
    for (int reg = 0; reg < 4; ++reg) {
      float rmax = fmaxf(fmaxf(s[0][reg], s[1][reg]), fmaxf(s[2][reg], s[3][reg]));
      rmax = fmaxf(rmax, __shfl_xor(rmax, 1));
      rmax = fmaxf(rmax, __shfl_xor(rmax, 2));
      rmax = fmaxf(rmax, __shfl_xor(rmax, 4));
      rmax = fmaxf(rmax, __shfl_xor(rmax, 8));
      float mnew = fmaxf(m_run[reg], rmax);
      float sc = __expf(m_run[reg] - mnew);
      m_run[reg] = mnew;
      l_run[reg] *= sc;
#pragma unroll
      for (int dt = 0; dt < 4; ++dt) oacc[dt][reg] *= sc;
      float rsum = 0.f;
#pragma unroll
      for (int jt = 0; jt < 4; ++jt) {
        float pexp = __expf(s[jt][reg] - mnew);
        s[jt][reg] = pexp;
        rsum += pexp;
      }
      rsum += __shfl_xor(rsum, 1);
      rsum += __shfl_xor(rsum, 2);
      rsum += __shfl_xor(rsum, 4);
      rsum += __shfl_xor(rsum, 8);
      l_run[reg] += rsum;
    }
    // P -> LDS (bf16) to re-fragment for PV (intra-wave only; no barrier needed)
#pragma unroll
    for (int jt = 0; jt < 4; ++jt)
#pragma unroll
      for (int reg = 0; reg < 4; ++reg)
        Ps[w][l4 * 4 + reg][jt * 16 + l15] = f2bf(s[jt][reg]);
    // O += P V   (A = P rows, B = V^T rows = contiguous kv)
#pragma unroll
    for (int ks = 0; ks < 2; ++ks) {
      bf16x8 pa = *(const bf16x8*)&Ps[w][l15][ks * 32 + l4 * 8];
#pragma unroll
      for (int dt = 0; dt < 4; ++dt) {
        bf16x8 vb = *(const bf16x8*)&Vs[dt * 16 + l15][ks * 32 + l4 * 8];
        oacc[dt] = mfma16(pa, vb, oacc[dt]);
      }
    }
  }

  // epilogue: O /= l, write bf16 [8192][1024]
#pragma unroll
  for (int reg = 0; reg < 4; ++reg) {
    float inv = 1.f / l_run[reg];
    int row = b * 1024 + q0 + w * 16 + l4 * 4 + reg;
#pragma unroll
    for (int dt = 0; dt < 4; ++dt)
      attn_out[(size_t)row * 1024 + h * 64 + dt * 16 + l15] = f2bf(oacc[dt][reg] * inv);
  }
}

extern "C" void kernel_launch(void* const* d_in, const int* in_sizes, int n_in,
                              void* d_out, int out_size, void* d_ws, size_t ws_size,
                              hipStream_t stream) {
  const float* x     = (const float*)d_in[0];
  const float* w_qkv = (const float*)d_in[1];
  const float* rpe   = (const float*)d_in[2];
  const float* w_out = (const float*)d_in[3];

  char* ws = (char*)d_ws;
  u16* wqkvT = (u16*)(ws);                       // [3072][1024]
  u16* woutT = (u16*)(ws + 6291456);             // [1024][1024]
  u16* qkv   = (u16*)(ws + 8388608);             // [8192][3072]
  u16* attnb = (u16*)(ws + 58720256);            // [8192][1024]

  dim3 tb(32, 8);
  transpose_cast_kernel<<<dim3(3072 / 32, 1024 / 32), tb, 0, stream>>>(w_qkv, wqkvT, 1024, 3072);
  transpose_cast_kernel<<<dim3(1024 / 32, 1024 / 32), tb, 0, stream>>>(w_out, woutT, 1024, 1024);

  gemm_kernel<true, false><<<dim3(3072 / 128, 8192 / 128), 256, 0, stream>>>(
      (const void*)x, wqkvT, (void*)qkv, 8192, 3072, 1024);

  attn_kernel<<<dim3(16, 128), 256, 0, stream>>>(qkv, rpe, attnb);

  gemm_kernel<false, true><<<dim3(1024 / 128, 8192 / 128), 256, 0, stream>>>(
      (const void*)attnb, woutT, d_out, 8192, 1024, 1024);
}

// Round 3
// 343.627 us; speedup vs baseline: 1.0474x; 1.0474x over previous
//
#include <hip/hip_runtime.h>

// Pipeline:
//  [C ] xb = bf16(x)                               [8192][1024]
//  [T1] wqkvT = bf16(w_qkv^T)   [T2] woutT = bf16(w_out^T)
//  [G1] qkv = xb @ w_qkv  -> scatter epilogue: qk [8192][2048] (q|k per head),
//                            vT [128 bh][64 d][1024 L]
//  [A ] flash attention (+rel-pos bias) -> attnb [8192][1024]  (aliases xb)
//  [G3] out = attnb @ w_out -> f32 d_out
//
// ws layout (72MB total):
//  xb/attnb @0 (16MB) | wqkvT @16MB (6MB) | woutT @22MB (2MB) | qk @24MB (32MB) | vT @56MB (16MB)

typedef __attribute__((ext_vector_type(8))) short bf16x8;
typedef __attribute__((ext_vector_type(4))) float f32x4;
typedef unsigned short u16;
typedef unsigned int u32;

__device__ __forceinline__ u16 f2bf(float f) {
  u32 u = __builtin_bit_cast(u32, f);
  u = (u + 0x7fffu + ((u >> 16) & 1u)) >> 16;
  return (u16)u;
}

__device__ __forceinline__ f32x4 mfma16(bf16x8 a, bf16x8 b, f32x4 c) {
  return __builtin_amdgcn_mfma_f32_16x16x32_bf16(a, b, c, 0, 0, 0);
}

__device__ __forceinline__ void gld_lds16(const u16* g, u16* l) {
  __builtin_amdgcn_global_load_lds(
      (const __attribute__((address_space(1))) unsigned int*)g,
      (__attribute__((address_space(3))) unsigned int*)l, 16, 0, 0);
}

// ---------------- cast f32 -> bf16, 8 elems/thread ----------------
__global__ __launch_bounds__(256) void cast_kernel(const float* __restrict__ in,
                                                   u16* __restrict__ out, int n8) {
  int i = blockIdx.x * 256 + threadIdx.x;
  if (i >= n8) return;
  float4 a = ((const float4*)in)[2 * i];
  float4 b = ((const float4*)in)[2 * i + 1];
  uint4 o;
  o.x = (u32)f2bf(a.x) | ((u32)f2bf(a.y) << 16);
  o.y = (u32)f2bf(a.z) | ((u32)f2bf(a.w) << 16);
  o.z = (u32)f2bf(b.x) | ((u32)f2bf(b.y) << 16);
  o.w = (u32)f2bf(b.z) | ((u32)f2bf(b.w) << 16);
  ((uint4*)out)[i] = o;
}

// ---------------- transpose + cast: in[R][C] f32 -> out[C][R] bf16 ----------------
__global__ __launch_bounds__(256) void transpose_cast_kernel(const float* __restrict__ in,
                                                             u16* __restrict__ out,
                                                             int R, int C) {
  __shared__ float tile[32][33];
  const int c0 = blockIdx.x * 32, r0 = blockIdx.y * 32;
  const int tx = threadIdx.x, ty = threadIdx.y;  // 32 x 8
#pragma unroll
  for (int i = 0; i < 32; i += 8)
    tile[ty + i][tx] = in[(size_t)(r0 + ty + i) * C + (c0 + tx)];
  __syncthreads();
#pragma unroll
  for (int i = 0; i < 32; i += 8)
    out[(size_t)(c0 + ty + i) * R + (r0 + tx)] = f2bf(tile[tx][ty + i]);
}

// ---------------- GEMM (m97 structure): C = A[M][K] @ BT[N][K]^T ----------------
// 128x128 tile, BK=64, 256 threads (2x2 waves x 64x64), linear LDS + global_load_lds x16.
// EPI 0: scatter q/k/vT (G1).  EPI 1: f32 out (G3).
template <int EPI>
__global__ __launch_bounds__(256) void gemm_kernel(const u16* __restrict__ A,
                                                   const u16* __restrict__ BT,
                                                   void* __restrict__ C0,
                                                   void* __restrict__ C1,
                                                   int M, int N, int K) {
  __shared__ u16 As[128][64];
  __shared__ u16 Bs[128][64];
  const int tid = threadIdx.x;
  const int lane = tid & 63, w = tid >> 6;
  const int wrow = w >> 1, wcol = w & 1;
  const int bm0 = blockIdx.y * 128, bn0 = blockIdx.x * 128;
  const int l15 = lane & 15, l4 = lane >> 4;
  const int lr = lane >> 3, lc = (lane & 7) * 8;  // staging: 8 rows/KB chunk, 8 cols/lane

  const f32x4 zero = {0.f, 0.f, 0.f, 0.f};
  f32x4 acc[4][4];
  for (int i = 0; i < 4; ++i)
    for (int j = 0; j < 4; ++j) acc[i][j] = zero;

  for (int k0 = 0; k0 < K; k0 += 64) {
    __syncthreads();
#pragma unroll
    for (int j = 0; j < 4; ++j) {
      int chunk = w * 4 + j;           // 0..15, 8 rows each
      int r = chunk * 8 + lr;
      gld_lds16(A + (size_t)(bm0 + r) * K + k0 + lc, &As[0][0] + chunk * 512);
      gld_lds16(BT + (size_t)(bn0 + r) * K + k0 + lc, &Bs[0][0] + chunk * 512);
    }
    __syncthreads();
#pragma unroll
    for (int ks = 0; ks < 2; ++ks) {
      bf16x8 afr[4], bfr[4];
#pragma unroll
      for (int mi = 0; mi < 4; ++mi)
        afr[mi] = *(const bf16x8*)&As[wrow * 64 + mi * 16 + l15][ks * 32 + l4 * 8];
#pragma unroll
      for (int ni = 0; ni < 4; ++ni)
        bfr[ni] = *(const bf16x8*)&Bs[wcol * 64 + ni * 16 + l15][ks * 32 + l4 * 8];
#pragma unroll
      for (int mi = 0; mi < 4; ++mi)
#pragma unroll
        for (int ni = 0; ni < 4; ++ni)
          acc[mi][ni] = mfma16(afr[mi], bfr[ni], acc[mi][ni]);
    }
  }

  const int rbase = bm0 + wrow * 64 + l4 * 4;
  const int cbase = bn0 + wcol * 64 + l15;
  if constexpr (EPI == 1) {
    float* C = (float*)C0;
#pragma unroll
    for (int mi = 0; mi < 4; ++mi)
#pragma unroll
      for (int reg = 0; reg < 4; ++reg)
#pragma unroll
        for (int ni = 0; ni < 4; ++ni)
          C[(size_t)(rbase + mi * 16 + reg) * N + cbase + ni * 16] = acc[mi][ni][reg];
  } else {
    // scatter: col n -> head h = n/192, sub = n%192. sub<128 -> qk[row][h*128+sub],
    // else vT[((b*16+h)*64 + sub-128)*1024 + l]
    u16* qk = (u16*)C0;
    u16* vT = (u16*)C1;
#pragma unroll
    for (int ni = 0; ni < 4; ++ni) {
      int n = cbase + ni * 16;
      int h = n / 192;
      int sub = n - h * 192;
#pragma unroll
      for (int mi = 0; mi < 4; ++mi)
#pragma unroll
        for (int reg = 0; reg < 4; ++reg) {
          int row = rbase + mi * 16 + reg;
          u16 v = f2bf(acc[mi][ni][reg]);
          if (sub < 128) {
            qk[(size_t)row * 2048 + h * 128 + sub] = v;
          } else {
            int b = row >> 10, l = row & 1023;
            vT[((size_t)(b * 16 + h) * 64 + (sub - 128)) * 1024 + l] = v;
          }
        }
    }
  }
}

// ---------------- flash attention with relative position bias ----------------
// qk[8192][2048]: row b*1024+l, cols h*128 + {0..63 q | 64..127 k}
// vT[128 bh][64 d][1024 kv]
// 1D grid 2048: bid = qt*128 + bh  (XCD = bh%8 -> all q-tiles of a head share an L2)
// 256 threads = 4 waves x 16 q-rows. KVBLK = 64. Softmax in log2 domain.
#define APAD 72
__global__ __launch_bounds__(256) void attn_kernel(const u16* __restrict__ qk,
                                                   const u16* __restrict__ vT,
                                                   const float* __restrict__ rpe,
                                                   u16* __restrict__ attn_out) {
  __shared__ u16 Ks[64][APAD];     // K tile [kv][d]
  __shared__ u16 Vs[64][APAD];     // V^T    [d][kv]
  __shared__ u16 Ps[4][16][APAD];  // per-wave P [q][kv]
  __shared__ float rpe_s[1087];    // rpe col h * log2(e), rows q0..q0+1086

  const int tid = threadIdx.x, lane = tid & 63, w = tid >> 6;
  const int l15 = lane & 15, l4 = lane >> 4;
  const int bid = blockIdx.x;
  const int qt = bid >> 7, bh = bid & 127;
  const int h = bh & 15, b = bh >> 4;
  const int q0 = qt * 64;
  const float LOG2E = 1.44269504f;

  for (int t = tid; t < 1087; t += 256)
    rpe_s[t] = rpe[(size_t)(q0 + t) * 16 + h] * LOG2E;

  // Q fragments (A row = lane&15, 8 contiguous d at l4*8)
  const u16* qbase = qk + ((size_t)(b * 1024 + q0 + w * 16) * 2048 + h * 128);
  bf16x8 aq[2];
#pragma unroll
  for (int ks = 0; ks < 2; ++ks)
    aq[ks] = *(const bf16x8*)(qbase + (size_t)l15 * 2048 + ks * 32 + l4 * 8);

  const f32x4 zero = {0.f, 0.f, 0.f, 0.f};
  float m_run[4], l_run[4];
  f32x4 oacc[4];
#pragma unroll
  for (int i = 0; i < 4; ++i) { m_run[i] = -1e30f; l_run[i] = 0.f; oacc[i] = zero; }

  const u16* kbase = qk + ((size_t)(b * 1024) * 2048 + h * 128 + 64);
  const u16* vbase = vT + (size_t)bh * 64 * 1024;

  for (int kt = 0; kt < 16; ++kt) {
    const int kv0 = kt * 64;
    __syncthreads();
    // stage K [64 kv][64 d] (row-major, vector loads, padded rows)
#pragma unroll
    for (int p = 0; p < 2; ++p) {
      int r = tid >> 2;
      int c = (p * 4 + (tid & 3)) * 8;
      *(uint4*)&Ks[r][c] = *(const uint4*)(kbase + (size_t)(kv0 + r) * 2048 + c);
    }
    // stage V^T [64 d][64 kv] (already transposed in global, vector loads)
#pragma unroll
    for (int p = 0; p < 2; ++p) {
      int r = tid >> 2;
      int c = (p * 4 + (tid & 3)) * 8;
      *(uint4*)&Vs[r][c] = *(const uint4*)(vbase + (size_t)r * 1024 + kv0 + c);
    }
    __syncthreads();

    // S = Q K^T  (B-fragment = K rows, contiguous d)
    f32x4 s[4];
#pragma unroll
    for (int jt = 0; jt < 4; ++jt) {
      f32x4 t = zero;
#pragma unroll
      for (int ks = 0; ks < 2; ++ks) {
        bf16x8 bk = *(const bf16x8*)&Ks[jt * 16 + l15][ks * 32 + l4 * 8];
        t = mfma16(aq[ks], bk, t);
      }
      s[jt] = t;
    }
    // log2-domain: s2 = s * (0.125*log2e) + bias*log2e
#pragma unroll
    for (int jt = 0; jt < 4; ++jt)
#pragma unroll
      for (int reg = 0; reg < 4; ++reg) {
        int idx = (w * 16 + l4 * 4 + reg) - (kv0 + jt * 16 + l15) + 1023;
        s[jt][reg] = s[jt][reg] * (0.125f * LOG2E) + rpe_s[idx];
      }
    // online softmax; q-row owned by (l4,reg), reduce across l15 (xor 1,2,4,8)
#pragma unroll
    for (int reg = 0; reg < 4; ++reg) {
      float rmax = fmaxf(fmaxf(s[0][reg], s[1][reg]), fmaxf(s[2][reg], s[3][reg]));
      rmax = fmaxf(rmax, __shfl_xor(rmax, 1));
      rmax = fmaxf(rmax, __shfl_xor(rmax, 2));
      rmax = fmaxf(rmax, __shfl_xor(rmax, 4));
      rmax = fmaxf(rmax, __shfl_xor(rmax, 8));
      float mnew = fmaxf(m_run[reg], rmax);
      float sc = __builtin_amdgcn_exp2f(m_run[reg] - mnew);
      m_run[reg] = mnew;
      l_run[reg] *= sc;
#pragma unroll
      for (int dt = 0; dt < 4; ++dt) oacc[dt][reg] *= sc;
      float rsum = 0.f;
#pragma unroll
      for (int jt = 0; jt < 4; ++jt) {
        float pexp = __builtin_amdgcn_exp2f(s[jt][reg] - mnew);
        s[jt][reg] = pexp;
        rsum += pexp;
      }
      rsum += __shfl_xor(rsum, 1);
      rsum += __shfl_xor(rsum, 2);
      rsum += __shfl_xor(rsum, 4);
      rsum += __shfl_xor(rsum, 8);
      l_run[reg] += rsum;
    }
    // P -> LDS (bf16) to re-fragment for PV (intra-wave, no barrier)
#pragma unroll
    for (int jt = 0; jt < 4; ++jt)
#pragma unroll
      for (int reg = 0; reg < 4; ++reg)
        Ps[w][l4 * 4 + reg][jt * 16 + l15] = f2bf(s[jt][reg]);
    // O += P V  (A = P rows, B = V^T rows = contiguous kv)
#pragma unroll
    for (int ks = 0; ks < 2; ++ks) {
      bf16x8 pa = *(const bf16x8*)&Ps[w][l15][ks * 32 + l4 * 8];
#pragma unroll
      for (int dt = 0; dt < 4; ++dt) {
        bf16x8 vb = *(const bf16x8*)&Vs[dt * 16 + l15][ks * 32 + l4 * 8];
        oacc[dt] = mfma16(pa, vb, oacc[dt]);
      }
    }
  }

  // epilogue: O /= l, write bf16 [8192][1024], col = h*64+d
#pragma unroll
  for (int reg = 0; reg < 4; ++reg) {
    float inv = 1.f / l_run[reg];
    int row = b * 1024 + q0 + w * 16 + l4 * 4 + reg;
#pragma unroll
    for (int dt = 0; dt < 4; ++dt)
      attn_out[(size_t)row * 1024 + h * 64 + dt * 16 + l15] = f2bf(oacc[dt][reg] * inv);
  }
}

extern "C" void kernel_launch(void* const* d_in, const int* in_sizes, int n_in,
                              void* d_out, int out_size, void* d_ws, size_t ws_size,
                              hipStream_t stream) {
  const float* x     = (const float*)d_in[0];
  const float* w_qkv = (const float*)d_in[1];
  const float* rpe   = (const float*)d_in[2];
  const float* w_out = (const float*)d_in[3];

  char* ws = (char*)d_ws;
  u16* xb    = (u16*)(ws);                 // [8192][1024]   (16MB)  — aliased:
  u16* attnb = (u16*)(ws);                 // [8192][1024]   (xb dead after G1)
  u16* wqkvT = (u16*)(ws + 16777216);      // [3072][1024]   (6MB)
  u16* woutT = (u16*)(ws + 23068672);      // [1024][1024]   (2MB)
  u16* qkbuf = (u16*)(ws + 25165824);      // [8192][2048]   (32MB)
  u16* vTbuf = (u16*)(ws + 58720256);      // [128][64][1024](16MB)

  cast_kernel<<<4096, 256, 0, stream>>>(x, xb, 8192 * 1024 / 8);
  dim3 tb(32, 8);
  transpose_cast_kernel<<<dim3(3072 / 32, 1024 / 32), tb, 0, stream>>>(w_qkv, wqkvT, 1024, 3072);
  transpose_cast_kernel<<<dim3(1024 / 32, 1024 / 32), tb, 0, stream>>>(w_out, woutT, 1024, 1024);

  gemm_kernel<0><<<dim3(3072 / 128, 8192 / 128), 256, 0, stream>>>(
      xb, wqkvT, (void*)qkbuf, (void*)vTbuf, 8192, 3072, 1024);

  attn_kernel<<<2048, 256, 0, stream>>>(qkbuf, vTbuf, rpe, attnb);

  gemm_kernel<1><<<dim3(1024 / 128, 8192 / 128), 256, 0, stream>>>(
      attnb, woutT, d_out, nullptr, 8192, 1024, 1024);
}

// Round 5
// 298.900 us; speedup vs baseline: 1.2041x; 1.1496x over previous
//
#include <hip/hip_runtime.h>

// Pipeline:
//  [C ] xb = bf16(x)                               [8192][1024]
//  [T1] wqkvT = bf16(w_qkv^T)   [T2] woutT = bf16(w_out^T)
//  [G1] qkv = xb @ w_qkv  -> epilogue: qk [8192][2048] (q|k per head),
//                            vT [128 bh][64 d][1024 L] (LDS bounce-transpose)
//  [A ] flash attention (+rel-pos bias) -> attnb [8192][1024]  (aliases xb)
//  [G3] out = attnb @ w_out -> f32 d_out
//
// ws layout (72MB total):
//  xb/attnb @0 (16MB) | wqkvT @16MB (6MB) | woutT @22MB (2MB) | qk @24MB (32MB) | vT @56MB (16MB)

typedef __attribute__((ext_vector_type(8))) short bf16x8;
typedef __attribute__((ext_vector_type(4))) float f32x4;
typedef unsigned short u16;
typedef unsigned int u32;

__device__ __forceinline__ u16 f2bf(float f) {
  u32 u = __builtin_bit_cast(u32, f);
  u = (u + 0x7fffu + ((u >> 16) & 1u)) >> 16;
  return (u16)u;
}

__device__ __forceinline__ f32x4 mfma16(bf16x8 a, bf16x8 b, f32x4 c) {
  return __builtin_amdgcn_mfma_f32_16x16x32_bf16(a, b, c, 0, 0, 0);
}

__device__ __forceinline__ void gld_lds16(const u16* g, u16* l) {
  __builtin_amdgcn_global_load_lds(
      (const __attribute__((address_space(1))) unsigned int*)g,
      (__attribute__((address_space(3))) unsigned int*)l, 16, 0, 0);
}

// ---------------- cast f32 -> bf16, 8 elems/thread ----------------
__global__ __launch_bounds__(256) void cast_kernel(const float* __restrict__ in,
                                                   u16* __restrict__ out, int n8) {
  int i = blockIdx.x * 256 + threadIdx.x;
  if (i >= n8) return;
  float4 a = ((const float4*)in)[2 * i];
  float4 b = ((const float4*)in)[2 * i + 1];
  uint4 o;
  o.x = (u32)f2bf(a.x) | ((u32)f2bf(a.y) << 16);
  o.y = (u32)f2bf(a.z) | ((u32)f2bf(a.w) << 16);
  o.z = (u32)f2bf(b.x) | ((u32)f2bf(b.y) << 16);
  o.w = (u32)f2bf(b.z) | ((u32)f2bf(b.w) << 16);
  ((uint4*)out)[i] = o;
}

// ---------------- transpose + cast: in[R][C] f32 -> out[C][R] bf16 ----------------
__global__ __launch_bounds__(256) void transpose_cast_kernel(const float* __restrict__ in,
                                                             u16* __restrict__ out,
                                                             int R, int C) {
  __shared__ float tile[32][33];
  const int c0 = blockIdx.x * 32, r0 = blockIdx.y * 32;
  const int tx = threadIdx.x, ty = threadIdx.y;  // 32 x 8
#pragma unroll
  for (int i = 0; i < 32; i += 8)
    tile[ty + i][tx] = in[(size_t)(r0 + ty + i) * C + (c0 + tx)];
  __syncthreads();
#pragma unroll
  for (int i = 0; i < 32; i += 8)
    out[(size_t)(c0 + ty + i) * R + (r0 + tx)] = f2bf(tile[tx][ty + i]);
}

// ---------------- GEMM (m97 structure): C = A[M][K] @ BT[N][K]^T ----------------
// 128x128 tile, BK=64, 256 threads (2x2 waves x 64x64), linear LDS + global_load_lds x16.
// EPI 0: qk direct stores + vT LDS bounce-transpose (G1).  EPI 1: f32 out (G3).
template <int EPI>
__global__ __launch_bounds__(256) void gemm_kernel(const u16* __restrict__ A,
                                                   const u16* __restrict__ BT,
                                                   void* __restrict__ C0,
                                                   void* __restrict__ C1,
                                                   int M, int N, int K) {
  __shared__ u16 As[128][64];
  __shared__ u16 Bs[128][64];
  const int tid = threadIdx.x;
  const int lane = tid & 63, w = tid >> 6;
  const int wrow = w >> 1, wcol = w & 1;
  const int bm0 = blockIdx.y * 128, bn0 = blockIdx.x * 128;
  const int l15 = lane & 15, l4 = lane >> 4;
  const int lr = lane >> 3, lc = (lane & 7) * 8;

  const f32x4 zero = {0.f, 0.f, 0.f, 0.f};
  f32x4 acc[4][4];
  for (int i = 0; i < 4; ++i)
    for (int j = 0; j < 4; ++j) acc[i][j] = zero;

  for (int k0 = 0; k0 < K; k0 += 64) {
    __syncthreads();
#pragma unroll
    for (int j = 0; j < 4; ++j) {
      int chunk = w * 4 + j;  // 0..15, 8 rows each
      int r = chunk * 8 + lr;
      gld_lds16(A + (size_t)(bm0 + r) * K + k0 + lc, &As[0][0] + chunk * 512);
      gld_lds16(BT + (size_t)(bn0 + r) * K + k0 + lc, &Bs[0][0] + chunk * 512);
    }
    __syncthreads();
#pragma unroll
    for (int ks = 0; ks < 2; ++ks) {
      bf16x8 afr[4], bfr[4];
#pragma unroll
      for (int mi = 0; mi < 4; ++mi)
        afr[mi] = *(const bf16x8*)&As[wrow * 64 + mi * 16 + l15][ks * 32 + l4 * 8];
#pragma unroll
      for (int ni = 0; ni < 4; ++ni)
        bfr[ni] = *(const bf16x8*)&Bs[wcol * 64 + ni * 16 + l15][ks * 32 + l4 * 8];
#pragma unroll
      for (int mi = 0; mi < 4; ++mi)
#pragma unroll
        for (int ni = 0; ni < 4; ++ni)
          acc[mi][ni] = mfma16(afr[mi], bfr[ni], acc[mi][ni]);
    }
  }

  const int rbase = bm0 + wrow * 64 + l4 * 4;
  const int cbase = bn0 + wcol * 64 + l15;
  if constexpr (EPI == 1) {
    float* C = (float*)C0;
#pragma unroll
    for (int mi = 0; mi < 4; ++mi)
#pragma unroll
      for (int reg = 0; reg < 4; ++reg)
#pragma unroll
        for (int ni = 0; ni < 4; ++ni)
          C[(size_t)(rbase + mi * 16 + reg) * N + cbase + ni * 16] = acc[mi][ni][reg];
  } else {
    __syncthreads();  // done with As frag reads; reuse As as bounce buffer
    u16* qkb = (u16*)C0;
    u16* vT = (u16*)C1;
    const int bq = bm0 >> 10;  // batch index (tile never straddles batch: 1024%128==0)
    u16* buf = &As[0][0] + w * 1024;  // per-wave 16n x 64m bounce tile
#pragma unroll
    for (int ni = 0; ni < 4; ++ni) {
      int n16 = bn0 + wcol * 64 + ni * 16;  // 16-col run never straddles 192/128 bounds
      int h = n16 / 192, sub = n16 - h * 192;
      if (sub < 128) {
#pragma unroll
        for (int mi = 0; mi < 4; ++mi)
#pragma unroll
          for (int reg = 0; reg < 4; ++reg) {
            int row = rbase + mi * 16 + reg;
            qkb[(size_t)row * 2048 + h * 128 + sub + l15] = f2bf(acc[mi][ni][reg]);
          }
      } else {
        asm volatile("s_waitcnt lgkmcnt(0)" ::: "memory");  // prev ni reads done
        // write [n=l15][m], xor-swizzled chunks
#pragma unroll
        for (int mi = 0; mi < 4; ++mi)
#pragma unroll
          for (int reg = 0; reg < 4; ++reg) {
            int ml = mi * 16 + l4 * 4 + reg;
            buf[l15 * 64 + (((ml >> 3) ^ (l15 & 7)) * 8) + (ml & 7)] =
                f2bf(acc[mi][ni][reg]);
          }
        asm volatile("s_waitcnt lgkmcnt(0)" ::: "memory");
        int dbase = sub - 128;
#pragma unroll
        for (int pass = 0; pass < 2; ++pass) {
          int nl = lane >> 2, c2 = (lane & 3) + pass * 4;
          uint4 val = *(uint4*)&buf[nl * 64 + ((c2 ^ (nl & 7)) * 8)];
          int m = bm0 + wrow * 64 + c2 * 8;
          *(uint4*)&vT[(((size_t)(bq * 16 + h) * 64 + (dbase + nl)) << 10) + (m & 1023)] =
              val;
        }
      }
    }
  }
}

// ---------------- flash attention with relative position bias ----------------
// qk[8192][2048]: row b*1024+l, cols h*128 + {0..63 q | 64..127 k}
// vT[128 bh][64 d][1024 kv]
// grid 2048: bid = qt*128 + bh (same-head q-tiles share an XCD/L2); qt in 0..15
// 256 threads = 4 waves x 16 q-rows. KVBLK = 128. XOR chunk-swizzled LDS.
__global__ __launch_bounds__(256) void attn_kernel(const u16* __restrict__ qk,
                                                   const u16* __restrict__ vT,
                                                   const float* __restrict__ rpe,
                                                   u16* __restrict__ attn_out) {
  __shared__ u16 Ks[128][64];      // K tile [kv][d], chunk ^= kv&7
  __shared__ u16 Vs[64][128];      // V^T    [d][kv], chunk ^= d&7
  __shared__ u16 Ps[4][16][128];   // per-wave P [q][kv], chunk ^= q&7
  __shared__ float rpe_s[1087];    // rpe col h * log2(e), rows q0..q0+1086

  const int tid = threadIdx.x, lane = tid & 63, w = tid >> 6;
  const int l15 = lane & 15, l4 = lane >> 4;
  const int bid = blockIdx.x;
  const int qt = bid >> 7, bh = bid & 127;
  const int h = bh & 15, b = bh >> 4;
  const int q0 = qt * 64;
  const float LOG2E = 1.44269504f;

  for (int t = tid; t < 1087; t += 256)
    rpe_s[t] = rpe[(size_t)(q0 + t) * 16 + h] * LOG2E;

  // Q fragments (A row = lane&15, 8 contiguous d at l4*8)
  const u16* qbase = qk + ((size_t)(b * 1024 + q0 + w * 16) * 2048 + h * 128);
  bf16x8 aq[2];
#pragma unroll
  for (int ks = 0; ks < 2; ++ks)
    aq[ks] = *(const bf16x8*)(qbase + (size_t)l15 * 2048 + ks * 32 + l4 * 8);

  const f32x4 zero = {0.f, 0.f, 0.f, 0.f};
  float m_run[4], l_run[4];
  f32x4 oacc[4];
#pragma unroll
  for (int i = 0; i < 4; ++i) { m_run[i] = -1e30f; l_run[i] = 0.f; oacc[i] = zero; }

  const u16* kbase = qk + ((size_t)(b * 1024) * 2048 + h * 128 + 64);
  const u16* vbase = vT + (size_t)bh * 64 * 1024;

  for (int kt = 0; kt < 8; ++kt) {
    const int kv0 = kt * 128;
    __syncthreads();
    // stage K [128 kv][64 d]: 4 passes, xor-swizzled chunks
#pragma unroll
    for (int p = 0; p < 4; ++p) {
      int r = p * 32 + (tid >> 3), c = tid & 7;
      *(uint4*)&Ks[r][(c ^ (r & 7)) * 8] =
          *(const uint4*)(kbase + (size_t)(kv0 + r) * 2048 + c * 8);
    }
    // stage V^T [64 d][128 kv]: 4 passes
#pragma unroll
    for (int p = 0; p < 4; ++p) {
      int r = p * 16 + (tid >> 4), c = tid & 15;
      *(uint4*)&Vs[r][(c ^ (r & 7)) * 8] =
          *(const uint4*)(vbase + (size_t)r * 1024 + kv0 + c * 8);
    }
    __syncthreads();

    // S = Q K^T (B-frag = K rows; swizzled chunk read)
    f32x4 s[8];
    __builtin_amdgcn_s_setprio(1);
#pragma unroll
    for (int jt = 0; jt < 8; ++jt) {
      f32x4 t = zero;
#pragma unroll
      for (int ks = 0; ks < 2; ++ks) {
        bf16x8 bk = *(const bf16x8*)&Ks[jt * 16 + l15][((ks * 4 + l4) ^ (l15 & 7)) * 8];
        t = mfma16(aq[ks], bk, t);
      }
      s[jt] = t;
    }
    __builtin_amdgcn_s_setprio(0);
    // scale + bias (log2 domain)
#pragma unroll
    for (int jt = 0; jt < 8; ++jt)
#pragma unroll
      for (int reg = 0; reg < 4; ++reg) {
        int idx = (w * 16 + l4 * 4 + reg) - (kv0 + jt * 16 + l15) + 1023;
        s[jt][reg] = s[jt][reg] * (0.125f * LOG2E) + rpe_s[idx];
      }
    // row max (reduce over l15 group), defer-rescale when no max grew
    float rmax[4];
    bool need = false;
#pragma unroll
    for (int reg = 0; reg < 4; ++reg) {
      float rm = fmaxf(fmaxf(s[0][reg], s[1][reg]), fmaxf(s[2][reg], s[3][reg]));
      rm = fmaxf(rm, fmaxf(fmaxf(s[4][reg], s[5][reg]), fmaxf(s[6][reg], s[7][reg])));
      rm = fmaxf(rm, __shfl_xor(rm, 1));
      rm = fmaxf(rm, __shfl_xor(rm, 2));
      rm = fmaxf(rm, __shfl_xor(rm, 4));
      rm = fmaxf(rm, __shfl_xor(rm, 8));
      rmax[reg] = rm;
      need = need || (rm > m_run[reg]);
    }
    if (__any(need)) {
#pragma unroll
      for (int reg = 0; reg < 4; ++reg) {
        float mnew = fmaxf(m_run[reg], rmax[reg]);
        float sc = __builtin_amdgcn_exp2f(m_run[reg] - mnew);
        m_run[reg] = mnew;
        l_run[reg] *= sc;
#pragma unroll
        for (int dt = 0; dt < 4; ++dt) oacc[dt][reg] *= sc;
      }
    }
    // p = exp2(s - m), accumulate l, write P to swizzled LDS
#pragma unroll
    for (int reg = 0; reg < 4; ++reg) {
      float rsum = 0.f;
      int q = l4 * 4 + reg;
#pragma unroll
      for (int jt = 0; jt < 8; ++jt) {
        float pexp = __builtin_amdgcn_exp2f(s[jt][reg] - m_run[reg]);
        rsum += pexp;
        Ps[w][q][(((jt * 2 + (l15 >> 3)) ^ (q & 7)) * 8) + (l15 & 7)] = f2bf(pexp);
      }
      rsum += __shfl_xor(rsum, 1);
      rsum += __shfl_xor(rsum, 2);
      rsum += __shfl_xor(rsum, 4);
      rsum += __shfl_xor(rsum, 8);
      l_run[reg] += rsum;
    }
    // O += P V (A = P rows [q=l15], B = V^T rows [d]; swizzled chunk reads)
    __builtin_amdgcn_s_setprio(1);
#pragma unroll
    for (int ksv = 0; ksv < 4; ++ksv) {
      bf16x8 pa = *(const bf16x8*)&Ps[w][l15][((ksv * 4 + l4) ^ (l15 & 7)) * 8];
#pragma unroll
      for (int dt = 0; dt < 4; ++dt) {
        bf16x8 vb = *(const bf16x8*)&Vs[dt * 16 + l15][((ksv * 4 + l4) ^ (l15 & 7)) * 8];
        oacc[dt] = mfma16(pa, vb, oacc[dt]);
      }
    }
    __builtin_amdgcn_s_setprio(0);
  }

  // epilogue: O /= l, write bf16 [8192][1024], col = h*64+d
#pragma unroll
  for (int reg = 0; reg < 4; ++reg) {
    float inv = 1.f / l_run[reg];
    int row = b * 1024 + q0 + w * 16 + l4 * 4 + reg;
#pragma unroll
    for (int dt = 0; dt < 4; ++dt)
      attn_out[(size_t)row * 1024 + h * 64 + dt * 16 + l15] = f2bf(oacc[dt][reg] * inv);
  }
}

extern "C" void kernel_launch(void* const* d_in, const int* in_sizes, int n_in,
                              void* d_out, int out_size, void* d_ws, size_t ws_size,
                              hipStream_t stream) {
  const float* x     = (const float*)d_in[0];
  const float* w_qkv = (const float*)d_in[1];
  const float* rpe   = (const float*)d_in[2];
  const float* w_out = (const float*)d_in[3];

  char* ws = (char*)d_ws;
  u16* xb    = (u16*)(ws);                 // [8192][1024]   (16MB)  — aliased:
  u16* attnb = (u16*)(ws);                 // [8192][1024]   (xb dead after G1)
  u16* wqkvT = (u16*)(ws + 16777216);      // [3072][1024]   (6MB)
  u16* woutT = (u16*)(ws + 23068672);      // [1024][1024]   (2MB)
  u16* qkbuf = (u16*)(ws + 25165824);      // [8192][2048]   (32MB)
  u16* vTbuf = (u16*)(ws + 58720256);      // [128][64][1024](16MB)

  cast_kernel<<<4096, 256, 0, stream>>>(x, xb, 8192 * 1024 / 8);
  dim3 tb(32, 8);
  transpose_cast_kernel<<<dim3(3072 / 32, 1024 / 32), tb, 0, stream>>>(w_qkv, wqkvT, 1024, 3072);
  transpose_cast_kernel<<<dim3(1024 / 32, 1024 / 32), tb, 0, stream>>>(w_out, woutT, 1024, 1024);

  gemm_kernel<0><<<dim3(3072 / 128, 8192 / 128), 256, 0, stream>>>(
      xb, wqkvT, (void*)qkbuf, (void*)vTbuf, 8192, 3072, 1024);

  attn_kernel<<<2048, 256, 0, stream>>>(qkbuf, vTbuf, rpe, attnb);

  gemm_kernel<1><<<dim3(1024 / 128, 8192 / 128), 256, 0, stream>>>(
      attnb, woutT, d_out, nullptr, 8192, 1024, 1024);
}

// Round 6
// 267.825 us; speedup vs baseline: 1.3438x; 1.1160x over previous
//
#include <hip/hip_runtime.h>

// Pipeline:
//  [C ] xb = bf16(x)                               [8192][1024]
//  [T1] wqkvT = bf16(w_qkv^T)   [P ] rpeT[h][idx] = rpe[idx][h]*log2e
//  [G1] qkv = xb @ w_qkv  -> epilogue: qk [8192][2048] (q|k per head),
//                            vT [128 bh][64 d][1024 L] (LDS bounce-transpose)
//  [A ] flash attention (+rel-pos bias) -> attnb [8192][1024]  (aliases xb)
//  [T2] woutT = bf16(w_out^T)   (after attn: rpeT aliases woutT slot)
//  [G3] out = attnb @ w_out -> f32 d_out
//
// ws layout (72MB total):
//  xb/attnb @0 (16MB) | wqkvT @16MB (6MB) | rpeT/woutT @22MB (2MB) |
//  qk @24MB (32MB) | vT @56MB (16MB)

typedef __attribute__((ext_vector_type(8))) short bf16x8;
typedef __attribute__((ext_vector_type(4))) float f32x4;
typedef unsigned short u16;
typedef unsigned int u32;

__device__ __forceinline__ u16 f2bf(float f) {
  u32 u = __builtin_bit_cast(u32, f);
  u = (u + 0x7fffu + ((u >> 16) & 1u)) >> 16;
  return (u16)u;
}

__device__ __forceinline__ f32x4 mfma16(bf16x8 a, bf16x8 b, f32x4 c) {
  return __builtin_amdgcn_mfma_f32_16x16x32_bf16(a, b, c, 0, 0, 0);
}

__device__ __forceinline__ void gld_lds16(const u16* g, u16* l) {
  __builtin_amdgcn_global_load_lds(
      (const __attribute__((address_space(1))) unsigned int*)g,
      (__attribute__((address_space(3))) unsigned int*)l, 16, 0, 0);
}

// ---------------- cast f32 -> bf16, 8 elems/thread ----------------
__global__ __launch_bounds__(256) void cast_kernel(const float* __restrict__ in,
                                                   u16* __restrict__ out, int n8) {
  int i = blockIdx.x * 256 + threadIdx.x;
  if (i >= n8) return;
  float4 a = ((const float4*)in)[2 * i];
  float4 b = ((const float4*)in)[2 * i + 1];
  uint4 o;
  o.x = (u32)f2bf(a.x) | ((u32)f2bf(a.y) << 16);
  o.y = (u32)f2bf(a.z) | ((u32)f2bf(a.w) << 16);
  o.z = (u32)f2bf(b.x) | ((u32)f2bf(b.y) << 16);
  o.w = (u32)f2bf(b.z) | ((u32)f2bf(b.w) << 16);
  ((uint4*)out)[i] = o;
}

// ---------------- transpose + cast: in[R][C] f32 -> out[C][R] bf16 ----------------
__global__ __launch_bounds__(256) void transpose_cast_kernel(const float* __restrict__ in,
                                                             u16* __restrict__ out,
                                                             int R, int C) {
  __shared__ float tile[32][33];
  const int c0 = blockIdx.x * 32, r0 = blockIdx.y * 32;
  const int tx = threadIdx.x, ty = threadIdx.y;  // 32 x 8
#pragma unroll
  for (int i = 0; i < 32; i += 8)
    tile[ty + i][tx] = in[(size_t)(r0 + ty + i) * C + (c0 + tx)];
  __syncthreads();
#pragma unroll
  for (int i = 0; i < 32; i += 8)
    out[(size_t)(c0 + ty + i) * R + (r0 + tx)] = f2bf(tile[tx][ty + i]);
}

// ---------------- rpe transpose prep: rpeT[16][2048] = rpe[i][h]*log2e ----------------
__global__ __launch_bounds__(256) void rpe_prep_kernel(const float* __restrict__ rpe,
                                                       float* __restrict__ rpeT) {
  int o = blockIdx.x * 256 + threadIdx.x;  // 32768 threads
  int h = o >> 11, i = o & 2047;
  if (i < 2047) rpeT[h * 2048 + i] = rpe[(size_t)i * 16 + h] * 1.44269504f;
}

// ---------------- GEMM (m97 structure): C = A[M][K] @ BT[N][K]^T ----------------
// 128x128 tile, BK=64, 256 threads (2x2 waves x 64x64), linear LDS + global_load_lds x16.
// EPI 0: qk direct stores + vT LDS bounce-transpose (G1).  EPI 1: f32 out (G3).
template <int EPI>
__global__ __launch_bounds__(256) void gemm_kernel(const u16* __restrict__ A,
                                                   const u16* __restrict__ BT,
                                                   void* __restrict__ C0,
                                                   void* __restrict__ C1,
                                                   int M, int N, int K) {
  __shared__ u16 As[128][64];
  __shared__ u16 Bs[128][64];
  const int tid = threadIdx.x;
  const int lane = tid & 63, w = tid >> 6;
  const int wrow = w >> 1, wcol = w & 1;
  const int bm0 = blockIdx.y * 128, bn0 = blockIdx.x * 128;
  const int l15 = lane & 15, l4 = lane >> 4;
  const int lr = lane >> 3, lc = (lane & 7) * 8;

  const f32x4 zero = {0.f, 0.f, 0.f, 0.f};
  f32x4 acc[4][4];
  for (int i = 0; i < 4; ++i)
    for (int j = 0; j < 4; ++j) acc[i][j] = zero;

  for (int k0 = 0; k0 < K; k0 += 64) {
    __syncthreads();
#pragma unroll
    for (int j = 0; j < 4; ++j) {
      int chunk = w * 4 + j;  // 0..15, 8 rows each
      int r = chunk * 8 + lr;
      gld_lds16(A + (size_t)(bm0 + r) * K + k0 + lc, &As[0][0] + chunk * 512);
      gld_lds16(BT + (size_t)(bn0 + r) * K + k0 + lc, &Bs[0][0] + chunk * 512);
    }
    __syncthreads();
#pragma unroll
    for (int ks = 0; ks < 2; ++ks) {
      bf16x8 afr[4], bfr[4];
#pragma unroll
      for (int mi = 0; mi < 4; ++mi)
        afr[mi] = *(const bf16x8*)&As[wrow * 64 + mi * 16 + l15][ks * 32 + l4 * 8];
#pragma unroll
      for (int ni = 0; ni < 4; ++ni)
        bfr[ni] = *(const bf16x8*)&Bs[wcol * 64 + ni * 16 + l15][ks * 32 + l4 * 8];
#pragma unroll
      for (int mi = 0; mi < 4; ++mi)
#pragma unroll
        for (int ni = 0; ni < 4; ++ni)
          acc[mi][ni] = mfma16(afr[mi], bfr[ni], acc[mi][ni]);
    }
  }

  const int rbase = bm0 + wrow * 64 + l4 * 4;
  const int cbase = bn0 + wcol * 64 + l15;
  if constexpr (EPI == 1) {
    float* C = (float*)C0;
#pragma unroll
    for (int mi = 0; mi < 4; ++mi)
#pragma unroll
      for (int reg = 0; reg < 4; ++reg)
#pragma unroll
        for (int ni = 0; ni < 4; ++ni)
          C[(size_t)(rbase + mi * 16 + reg) * N + cbase + ni * 16] = acc[mi][ni][reg];
  } else {
    __syncthreads();  // done with As frag reads; reuse As as bounce buffer
    u16* qkb = (u16*)C0;
    u16* vT = (u16*)C1;
    const int bq = bm0 >> 10;  // batch index (tile never straddles batch: 1024%128==0)
    u16* buf = &As[0][0] + w * 1024;  // per-wave 16n x 64m bounce tile
#pragma unroll
    for (int ni = 0; ni < 4; ++ni) {
      int n16 = bn0 + wcol * 64 + ni * 16;  // 16-col run never straddles 192/128 bounds
      int h = n16 / 192, sub = n16 - h * 192;
      if (sub < 128) {
#pragma unroll
        for (int mi = 0; mi < 4; ++mi)
#pragma unroll
          for (int reg = 0; reg < 4; ++reg) {
            int row = rbase + mi * 16 + reg;
            qkb[(size_t)row * 2048 + h * 128 + sub + l15] = f2bf(acc[mi][ni][reg]);
          }
      } else {
        asm volatile("s_waitcnt lgkmcnt(0)" ::: "memory");  // prev ni reads done
        // write [n=l15][m], xor-swizzled chunks
#pragma unroll
        for (int mi = 0; mi < 4; ++mi)
#pragma unroll
          for (int reg = 0; reg < 4; ++reg) {
            int ml = mi * 16 + l4 * 4 + reg;
            buf[l15 * 64 + (((ml >> 3) ^ (l15 & 7)) * 8) + (ml & 7)] =
                f2bf(acc[mi][ni][reg]);
          }
        asm volatile("s_waitcnt lgkmcnt(0)" ::: "memory");
        int dbase = sub - 128;
#pragma unroll
        for (int pass = 0; pass < 2; ++pass) {
          int nl = lane >> 2, c2 = (lane & 3) + pass * 4;
          uint4 val = *(uint4*)&buf[nl * 64 + ((c2 ^ (nl & 7)) * 8)];
          int m = bm0 + wrow * 64 + c2 * 8;
          *(uint4*)&vT[(((size_t)(bq * 16 + h) * 64 + (dbase + nl)) << 10) + (m & 1023)] =
              val;
        }
      }
    }
  }
}

// ---------------- flash attention with relative position bias ----------------
// qk[8192][2048]: row b*1024+l, cols h*128 + {0..63 q | 64..127 k}
// vT[128 bh][64 d][1024 kv] ; rpeT[16][2048] (pre-scaled by log2e)
// grid 1024: bid = qt*128 + bh (qt 0..7, QBLK=128); same-head blocks share XCD L2.
// 512 threads = 8 waves x 16 q-rows. KVBLK = 128.
// Swapped QK^T: S^T = mfma(K, Q): lane owns ONE q-row (q = w*16+l15), kv = jt*16+l4*4+reg.
// K/V staged via global_load_lds with pre-swizzled SOURCE (linear LDS dest).
__global__ __launch_bounds__(512, 4) void attn_kernel(const u16* __restrict__ qk,
                                                      const u16* __restrict__ vT,
                                                      const float* __restrict__ rpeT,
                                                      u16* __restrict__ attn_out) {
  __shared__ u16 Ks[128][64];     // K tile [kv][d], chunk c holds global chunk c^(kv&7)
  __shared__ u16 Vs[64][128];     // V^T    [d][kv], chunk c holds global chunk c^(d&7)
  __shared__ u16 Ps[8][16][128];  // per-wave P [q][kv], chunk ^= q&7
  __shared__ float rpe_s[1152];   // rpeT[h][q0 .. q0+1150]

  const int tid = threadIdx.x, lane = tid & 63, w = tid >> 6;
  const int l15 = lane & 15, l4 = lane >> 4;
  const int bid = blockIdx.x;
  const int qt = bid >> 7, bh = bid & 127;
  const int h = bh & 15, b = bh >> 4;
  const int q0 = qt * 128;

  for (int t = tid; t < 1151; t += 512)
    rpe_s[t] = rpeT[h * 2048 + q0 + t];

  // Q fragments (B operand): col = l15 -> q row = q0 + w*16 + l15; k(d) at ks*32+l4*8
  const u16* qbase = qk + ((size_t)(b * 1024 + q0 + w * 16 + l15) * 2048 + h * 128);
  bf16x8 bq0 = *(const bf16x8*)(qbase + l4 * 8);
  bf16x8 bq1 = *(const bf16x8*)(qbase + 32 + l4 * 8);

  const f32x4 zero = {0.f, 0.f, 0.f, 0.f};
  float m_run = -1e30f, l_run = 0.f;
  f32x4 oacc[4];
#pragma unroll
  for (int i = 0; i < 4; ++i) oacc[i] = zero;

  const u16* kgbase = qk + ((size_t)(b * 1024) * 2048 + h * 128 + 64);
  const u16* vgbase = vT + (size_t)bh * 65536;

  for (int kt = 0; kt < 8; ++kt) {
    const int kv0 = kt * 128;
    __syncthreads();
    // stage K [128 kv][64 d] + V^T [64 d][128 kv]: gld_lds, linear LDS dest,
    // inverse-swizzled global source (coalescing preserved: permutation within row)
#pragma unroll
    for (int p = 0; p < 2; ++p) {
      int e = p * 512 + tid;
      int kr = e >> 3, kc = e & 7;
      gld_lds16(kgbase + (size_t)(kv0 + kr) * 2048 + ((kc ^ (kr & 7)) * 8),
                &Ks[0][0] + (size_t)(p * 512 + w * 64) * 8);
      int vr = e >> 4, vc = e & 15;
      gld_lds16(vgbase + (size_t)vr * 1024 + kv0 + ((vc ^ (vr & 7)) * 8),
                &Vs[0][0] + (size_t)(p * 512 + w * 64) * 8);
    }
    __syncthreads();

    // S^T = K Q^T : A = K rows (row=l15 -> kv jt*16+l15), B = Q (col=l15 -> q)
    // D: col=l15=q, row=l4*4+reg = kv within jt
    f32x4 s[8];
    __builtin_amdgcn_s_setprio(1);
#pragma unroll
    for (int jt = 0; jt < 8; ++jt) {
      f32x4 t = zero;
      bf16x8 ak0 = *(const bf16x8*)&Ks[jt * 16 + l15][((l4) ^ (l15 & 7)) * 8];
      bf16x8 ak1 = *(const bf16x8*)&Ks[jt * 16 + l15][((4 + l4) ^ (l15 & 7)) * 8];
      t = mfma16(ak0, bq0, t);
      t = mfma16(ak1, bq1, t);
      s[jt] = t;
    }
    __builtin_amdgcn_s_setprio(0);

    // bias: idx_local = (q - kv + 1023) - q0 = w*16+l15+1023-kv0 - jt*16 - l4*4 - reg
    const int ibase = w * 16 + l15 + 1023 - kv0 - l4 * 4;
#pragma unroll
    for (int jt = 0; jt < 8; ++jt)
#pragma unroll
      for (int reg = 0; reg < 4; ++reg)
        s[jt][reg] = s[jt][reg] * (0.125f * 1.44269504f) + rpe_s[ibase - jt * 16 - reg];

    // per-lane row max over 32 in-lane values + 2 cross-l4 shuffles
    float rm = fmaxf(fmaxf(s[0][0], s[0][1]), fmaxf(s[0][2], s[0][3]));
#pragma unroll
    for (int jt = 1; jt < 8; ++jt)
      rm = fmaxf(rm, fmaxf(fmaxf(s[jt][0], s[jt][1]), fmaxf(s[jt][2], s[jt][3])));
    rm = fmaxf(rm, __shfl_xor(rm, 16));
    rm = fmaxf(rm, __shfl_xor(rm, 32));

    if (__any(rm > m_run)) {
      float mnew = fmaxf(m_run, rm);
      float sc = __builtin_amdgcn_exp2f(m_run - mnew);
      m_run = mnew;
      l_run *= sc;
      // oacc rows are q' = l4*4+reg -> fetch that row's sc from lane l4*4+reg
#pragma unroll
      for (int reg = 0; reg < 4; ++reg) {
        float scr = __shfl(sc, l4 * 4 + reg);
#pragma unroll
        for (int dt = 0; dt < 4; ++dt) oacc[dt][reg] *= scr;
      }
    }

    // p = exp2(s - m); sum in-lane; pack consecutive-kv pairs via cvt_pk; store Ps
    float rsum = 0.f;
#pragma unroll
    for (int jt = 0; jt < 8; ++jt) {
      float p0 = __builtin_amdgcn_exp2f(s[jt][0] - m_run);
      float p1 = __builtin_amdgcn_exp2f(s[jt][1] - m_run);
      float p2 = __builtin_amdgcn_exp2f(s[jt][2] - m_run);
      float p3 = __builtin_amdgcn_exp2f(s[jt][3] - m_run);
      rsum += (p0 + p1) + (p2 + p3);
      u32 pk01, pk23;
      asm("v_cvt_pk_bf16_f32 %0, %1, %2" : "=v"(pk01) : "v"(p0), "v"(p1));
      asm("v_cvt_pk_bf16_f32 %0, %1, %2" : "=v"(pk23) : "v"(p2), "v"(p3));
      // kv_local = jt*16 + l4*4 + {0..3}: chunk = jt*2+(l4>>1), off = (l4&1)*4
      int chunk = (jt * 2 + (l4 >> 1)) ^ (l15 & 7);
      u32* dst = (u32*)&Ps[w][l15][chunk * 8 + (l4 & 1) * 4];
      dst[0] = pk01;
      dst[1] = pk23;
    }
    rsum += __shfl_xor(rsum, 16);
    rsum += __shfl_xor(rsum, 32);
    l_run += rsum;

    // O += P V : A = P (row=l15=q, kv at (ksv*4+l4)*8 swizzled by q&7),
    //            B = V^T rows (col=l15 -> d, kv contiguous)
    __builtin_amdgcn_s_setprio(1);
#pragma unroll
    for (int ksv = 0; ksv < 4; ++ksv) {
      bf16x8 pa = *(const bf16x8*)&Ps[w][l15][((ksv * 4 + l4) ^ (l15 & 7)) * 8];
#pragma unroll
      for (int dt = 0; dt < 4; ++dt) {
        bf16x8 vb = *(const bf16x8*)&Vs[dt * 16 + l15][((ksv * 4 + l4) ^ (l15 & 7)) * 8];
        oacc[dt] = mfma16(pa, vb, oacc[dt]);
      }
    }
    __builtin_amdgcn_s_setprio(0);
  }

  // epilogue: O[q'=l4*4+reg][d=dt*16+l15] /= l(q'); l lives at lane l4*4+reg
  float inv = 1.f / l_run;
#pragma unroll
  for (int reg = 0; reg < 4; ++reg) {
    float invr = __shfl(inv, l4 * 4 + reg);
    int row = b * 1024 + q0 + w * 16 + l4 * 4 + reg;
#pragma unroll
    for (int dt = 0; dt < 4; ++dt)
      attn_out[(size_t)row * 1024 + h * 64 + dt * 16 + l15] = f2bf(oacc[dt][reg] * invr);
  }
}

extern "C" void kernel_launch(void* const* d_in, const int* in_sizes, int n_in,
                              void* d_out, int out_size, void* d_ws, size_t ws_size,
                              hipStream_t stream) {
  const float* x     = (const float*)d_in[0];
  const float* w_qkv = (const float*)d_in[1];
  const float* rpe   = (const float*)d_in[2];
  const float* w_out = (const float*)d_in[3];

  char* ws = (char*)d_ws;
  u16* xb    = (u16*)(ws);                 // [8192][1024]   (16MB)  — aliased:
  u16* attnb = (u16*)(ws);                 // [8192][1024]   (xb dead after G1)
  u16* wqkvT = (u16*)(ws + 16777216);      // [3072][1024]   (6MB)
  u16* woutT = (u16*)(ws + 23068672);      // [1024][1024]   (2MB)  — aliased:
  float* rpeT = (float*)(ws + 23068672);   // [16][2048] f32 (rpeT dead before T2 writes)
  u16* qkbuf = (u16*)(ws + 25165824);      // [8192][2048]   (32MB)
  u16* vTbuf = (u16*)(ws + 58720256);      // [128][64][1024](16MB)

  cast_kernel<<<4096, 256, 0, stream>>>(x, xb, 8192 * 1024 / 8);
  dim3 tb(32, 8);
  transpose_cast_kernel<<<dim3(3072 / 32, 1024 / 32), tb, 0, stream>>>(w_qkv, wqkvT, 1024, 3072);
  rpe_prep_kernel<<<128, 256, 0, stream>>>(rpe, rpeT);

  gemm_kernel<0><<<dim3(3072 / 128, 8192 / 128), 256, 0, stream>>>(
      xb, wqkvT, (void*)qkbuf, (void*)vTbuf, 8192, 3072, 1024);

  attn_kernel<<<1024, 512, 0, stream>>>(qkbuf, vTbuf, rpeT, attnb);

  transpose_cast_kernel<<<dim3(1024 / 32, 1024 / 32), tb, 0, stream>>>(w_out, woutT, 1024, 1024);

  gemm_kernel<1><<<dim3(1024 / 128, 8192 / 128), 256, 0, stream>>>(
      attnb, woutT, d_out, nullptr, 8192, 1024, 1024);
}

// Round 7
// 265.932 us; speedup vs baseline: 1.3534x; 1.0071x over previous
//
#include <hip/hip_runtime.h>

// Pipeline:
//  [C ] xb = bf16(x)                               [8192][1024]
//  [T1] wqkvT = bf16(w_qkv^T)   [P ] rpeT[h][idx] = rpe[idx][h]*log2e
//  [G1] qkv = xb @ w_qkv (256^2 8-phase) -> qk [8192][2048], vT [128][64][1024]
//  [A ] flash attention (+rel-pos bias) -> attnb [8192][1024]  (aliases xb)
//  [T2] woutT = bf16(w_out^T)
//  [G3] out = attnb @ w_out (256^2 8-phase) -> f32 d_out
//
// ws layout (72MB): xb/attnb @0 (16MB) | wqkvT @16MB (6MB) | rpeT/woutT @22MB (2MB)
//                   | qk @24MB (32MB) | vT @56MB (16MB)

typedef __attribute__((ext_vector_type(8))) short bf16x8;
typedef __attribute__((ext_vector_type(4))) float f32x4;
typedef unsigned short u16;
typedef unsigned int u32;

__device__ __forceinline__ u16 f2bf(float f) {
  u32 u = __builtin_bit_cast(u32, f);
  u = (u + 0x7fffu + ((u >> 16) & 1u)) >> 16;
  return (u16)u;
}

__device__ __forceinline__ f32x4 mfma16(bf16x8 a, bf16x8 b, f32x4 c) {
  return __builtin_amdgcn_mfma_f32_16x16x32_bf16(a, b, c, 0, 0, 0);
}

__device__ __forceinline__ void gld_lds16(const u16* g, u16* l) {
  __builtin_amdgcn_global_load_lds(
      (const __attribute__((address_space(1))) unsigned int*)g,
      (__attribute__((address_space(3))) unsigned int*)l, 16, 0, 0);
}

#define BARRIER() asm volatile("s_barrier" ::: "memory")
#define VMCNT4() asm volatile("s_waitcnt vmcnt(4)" ::: "memory")
#define VMCNT0() asm volatile("s_waitcnt vmcnt(0)" ::: "memory")

// ---------------- cast f32 -> bf16, 8 elems/thread ----------------
__global__ __launch_bounds__(256) void cast_kernel(const float* __restrict__ in,
                                                   u16* __restrict__ out, int n8) {
  int i = blockIdx.x * 256 + threadIdx.x;
  if (i >= n8) return;
  float4 a = ((const float4*)in)[2 * i];
  float4 b = ((const float4*)in)[2 * i + 1];
  uint4 o;
  o.x = (u32)f2bf(a.x) | ((u32)f2bf(a.y) << 16);
  o.y = (u32)f2bf(a.z) | ((u32)f2bf(a.w) << 16);
  o.z = (u32)f2bf(b.x) | ((u32)f2bf(b.y) << 16);
  o.w = (u32)f2bf(b.z) | ((u32)f2bf(b.w) << 16);
  ((uint4*)out)[i] = o;
}

// ---------------- transpose + cast: in[R][C] f32 -> out[C][R] bf16 ----------------
__global__ __launch_bounds__(256) void transpose_cast_kernel(const float* __restrict__ in,
                                                             u16* __restrict__ out,
                                                             int R, int C) {
  __shared__ float tile[32][33];
  const int c0 = blockIdx.x * 32, r0 = blockIdx.y * 32;
  const int tx = threadIdx.x, ty = threadIdx.y;  // 32 x 8
#pragma unroll
  for (int i = 0; i < 32; i += 8)
    tile[ty + i][tx] = in[(size_t)(r0 + ty + i) * C + (c0 + tx)];
  __syncthreads();
#pragma unroll
  for (int i = 0; i < 32; i += 8)
    out[(size_t)(c0 + ty + i) * R + (r0 + tx)] = f2bf(tile[tx][ty + i]);
}

// ---------------- rpe transpose prep: rpeT[16][2048] = rpe[i][h]*log2e ----------------
__global__ __launch_bounds__(256) void rpe_prep_kernel(const float* __restrict__ rpe,
                                                       float* __restrict__ rpeT) {
  int o = blockIdx.x * 256 + threadIdx.x;
  int h = o >> 11, i = o & 2047;
  if (i < 2047) rpeT[h * 2048 + i] = rpe[(size_t)i * 16 + h] * 1.44269504f;
}

// ---------------- 256x256 8-phase GEMM: C = A[M][K] @ BT[N][K]^T ----------------
// 512 threads = 8 waves (2M x 4N), per-wave 128x64 out. BK=64, nt=K/64 tiles.
// LDS: 2 x (A[256][64] + B[256][64]) = 128KB, XOR chunk-swizzle (c ^= row&7).
// Per tile, 4 phases (one C-quadrant x K=64 each, 16 MFMA), 1 half-tile staged/phase,
// counted vmcnt(4) once per tile. Prefetch overwrite is >=1 full phase after the
// region's last reader (A-halves die ph3, B-halves die ph2) -> race-free by barriers.
// EPI 0: qk scatter + vT LDS bounce-transpose (G1).  EPI 1: f32 out (G3).
template <int EPI>
__global__ __launch_bounds__(512, 2) void gemm2_kernel(const u16* __restrict__ A,
                                                       const u16* __restrict__ BT,
                                                       void* __restrict__ C0,
                                                       void* __restrict__ C1,
                                                       int M, int N, int K, int ny) {
  __shared__ u16 LA[2][256][64];
  __shared__ u16 LB[2][256][64];
  const int tid = threadIdx.x, lane = tid & 63, w = tid >> 6;
  const int wm = w >> 2, wn = w & 3;
  const int l15 = lane & 15, l4 = lane >> 4;
  const int e7 = l15 & 7;

  // XCD-swizzled 1D grid -> (bx, by), x-outer (same-bx blocks share an XCD/L2)
  const int nwg = gridDim.x;
  const int virt = ((int)blockIdx.x & 7) * (nwg >> 3) + ((int)blockIdx.x >> 3);
  const int bx = virt / ny, by = virt % ny;
  const int bm0 = by * 256, bn0 = bx * 256;
  const int nt = K >> 6;

  const int sr = tid >> 3, sc = tid & 7;  // staging row/chunk within 64-row sweep

  auto stageA = [&](int buf, int half, int kt) {
#pragma unroll
    for (int s = 0; s < 2; ++s) {
      int r = s * 64 + sr;
      gld_lds16(A + (size_t)(bm0 + half * 128 + r) * K + kt * 64 + ((sc ^ (r & 7)) * 8),
                &LA[buf][half * 128][0] + s * 4096 + tid * 8);
    }
  };
  auto stageB = [&](int buf, int half, int kt) {
#pragma unroll
    for (int s = 0; s < 2; ++s) {
      int r = s * 64 + sr;
      gld_lds16(BT + (size_t)(bn0 + half * 128 + r) * K + kt * 64 + ((sc ^ (r & 7)) * 8),
                &LB[buf][half * 128][0] + s * 4096 + tid * 8);
    }
  };

  const f32x4 zero = {0.f, 0.f, 0.f, 0.f};
  f32x4 acc[8][4];
#pragma unroll
  for (int i = 0; i < 8; ++i)
#pragma unroll
    for (int j = 0; j < 4; ++j) acc[i][j] = zero;

  bf16x8 afr[8], bf0[4], bf1[4];

  auto ldA = [&](int bt, int mh) {
#pragma unroll
    for (int mi2 = 0; mi2 < 4; ++mi2)
#pragma unroll
      for (int ks = 0; ks < 2; ++ks)
        afr[mi2 * 2 + ks] = *(const bf16x8*)&LA[bt][wm * 128 + mh * 64 + mi2 * 16 + l15]
                                               [((ks * 4 + l4) ^ e7) * 8];
  };
  auto ldB = [&](int bt, int nh, bf16x8* bfr) {
#pragma unroll
    for (int ni2 = 0; ni2 < 2; ++ni2)
#pragma unroll
      for (int ks = 0; ks < 2; ++ks)
        bfr[ni2 * 2 + ks] = *(const bf16x8*)&LB[bt][wn * 64 + (nh * 2 + ni2) * 16 + l15]
                                                [((ks * 4 + l4) ^ e7) * 8];
  };
  auto quad = [&](int mh, int nh, bf16x8* bfr) {
    __builtin_amdgcn_s_setprio(1);
#pragma unroll
    for (int mi2 = 0; mi2 < 4; ++mi2)
#pragma unroll
      for (int ni2 = 0; ni2 < 2; ++ni2)
#pragma unroll
        for (int ks = 0; ks < 2; ++ks)
          acc[mh * 4 + mi2][nh * 2 + ni2] =
              mfma16(afr[mi2 * 2 + ks], bfr[ni2 * 2 + ks], acc[mh * 4 + mi2][nh * 2 + ni2]);
    __builtin_amdgcn_s_setprio(0);
  };

  // prologue: tile0 fully + tile1's B halves; wait tile0 (4 loads may stay in flight)
  stageA(0, 0, 0);
  stageA(0, 1, 0);
  stageB(0, 0, 0);
  stageB(0, 1, 0);
  if (nt > 1) {
    stageB(1, 0, 1);
    stageB(1, 1, 1);
  }
  VMCNT4();
  BARRIER();

  for (int t = 0; t < nt; ++t) {
    const int bt = t & 1;
    // ph1: A(mh0) + B(nh0) reads; stage next tile's A-lo
    ldA(bt, 0);
    ldB(bt, 0, bf0);
    if (t + 1 < nt) stageA(bt ^ 1, 0, t + 1);
    BARRIER();
    quad(0, 0, bf0);
    BARRIER();
    // ph2: B(nh1) reads; stage next tile's A-hi
    ldB(bt, 1, bf1);
    if (t + 1 < nt) stageA(bt ^ 1, 1, t + 1);
    BARRIER();
    quad(0, 1, bf1);
    BARRIER();
    // ph3: A(mh1) reads; stage tile t+2's B-lo (B region dead after ph2)
    ldA(bt, 1);
    if (t + 2 < nt) stageB(bt, 0, t + 2);
    BARRIER();
    quad(1, 0, bf0);
    BARRIER();
    // ph4: stage tile t+2's B-hi; counted vmcnt -> tile t+1 complete
    if (t + 2 < nt) stageB(bt, 1, t + 2);
    if (t < nt - 2) {
      VMCNT4();
    } else {
      VMCNT0();
    }
    BARRIER();
    quad(1, 1, bf1);
    BARRIER();
  }

  const int rbase = bm0 + wm * 128 + l4 * 4;
  const int cbase = bn0 + wn * 64 + l15;
  if constexpr (EPI == 1) {
    float* C = (float*)C0;
#pragma unroll
    for (int mi = 0; mi < 8; ++mi)
#pragma unroll
      for (int reg = 0; reg < 4; ++reg)
#pragma unroll
        for (int ni = 0; ni < 4; ++ni)
          C[(size_t)(rbase + mi * 16 + reg) * N + cbase + ni * 16] = acc[mi][ni][reg];
  } else {
    u16* qkb = (u16*)C0;
    u16* vT = (u16*)C1;
    const int bq = bm0 >> 10;  // tile never straddles batch (1024 % 256 == 0)
    u16* bbuf = &LA[0][0][0] + w * 2048;  // per-wave 16(n) x 128(m) bounce tile
#pragma unroll
    for (int ni = 0; ni < 4; ++ni) {
      int n16 = bn0 + wn * 64 + ni * 16;  // 16-col run never straddles q/k/v bounds
      int h = n16 / 192, sub = n16 - h * 192;
      if (sub < 128) {
#pragma unroll
        for (int mi = 0; mi < 8; ++mi)
#pragma unroll
          for (int reg = 0; reg < 4; ++reg) {
            int row = rbase + mi * 16 + reg;
            qkb[(size_t)row * 2048 + h * 128 + sub + l15] = f2bf(acc[mi][ni][reg]);
          }
      } else {
        asm volatile("s_waitcnt lgkmcnt(0)" ::: "memory");  // prev ni reads done
#pragma unroll
        for (int mi = 0; mi < 8; ++mi)
#pragma unroll
          for (int reg = 0; reg < 4; ++reg) {
            int ml = mi * 16 + l4 * 4 + reg;
            bbuf[l15 * 128 + (((ml >> 3) ^ e7) * 8) + (ml & 7)] = f2bf(acc[mi][ni][reg]);
          }
        asm volatile("s_waitcnt lgkmcnt(0)" ::: "memory");
        int dsub = sub - 128;
#pragma unroll
        for (int pass = 0; pass < 4; ++pass) {
          int nl = lane >> 2, cc = (lane & 3) + pass * 4;
          uint4 val = *(uint4*)&bbuf[nl * 128 + ((cc ^ (nl & 7)) * 8)];
          int mg = bm0 + wm * 128 + cc * 8;
          *(uint4*)&vT[(((size_t)(bq * 16 + h) * 64 + (dsub + nl)) << 10) + (mg & 1023)] =
              val;
        }
      }
    }
  }
}

// ---------------- flash attention with relative position bias ----------------
// qk[8192][2048]: row b*1024+l, cols h*128 + {0..63 q | 64..127 k}
// vT[128 bh][64 d][1024 kv] ; rpeT[16][2048] (pre-scaled by log2e)
// grid 1024: bid = qt*128 + bh (qt 0..7, QBLK=128); same-head blocks share XCD L2.
// 512 threads = 8 waves x 16 q-rows. KVBLK = 128.
// Swapped QK^T: lane owns ONE q-row (q = w*16+l15), kv = jt*16+l4*4+reg.
__global__ __launch_bounds__(512, 4) void attn_kernel(const u16* __restrict__ qk,
                                                      const u16* __restrict__ vT,
                                                      const float* __restrict__ rpeT,
                                                      u16* __restrict__ attn_out) {
  __shared__ u16 Ks[128][64];     // K tile [kv][d], chunk c holds global chunk c^(kv&7)
  __shared__ u16 Vs[64][128];     // V^T    [d][kv], chunk c holds global chunk c^(d&7)
  __shared__ u16 Ps[8][16][128];  // per-wave P [q][kv], chunk ^= q&7
  __shared__ float rpe_s[1152];   // rpeT[h][q0 .. q0+1150]

  const int tid = threadIdx.x, lane = tid & 63, w = tid >> 6;
  const int l15 = lane & 15, l4 = lane >> 4;
  const int bid = blockIdx.x;
  const int qt = bid >> 7, bh = bid & 127;
  const int h = bh & 15, b = bh >> 4;
  const int q0 = qt * 128;

  for (int t = tid; t < 1151; t += 512)
    rpe_s[t] = rpeT[h * 2048 + q0 + t];

  const u16* qbase = qk + ((size_t)(b * 1024 + q0 + w * 16 + l15) * 2048 + h * 128);
  bf16x8 bq0 = *(const bf16x8*)(qbase + l4 * 8);
  bf16x8 bq1 = *(const bf16x8*)(qbase + 32 + l4 * 8);

  const f32x4 zero = {0.f, 0.f, 0.f, 0.f};
  float m_run = -1e30f, l_run = 0.f;
  f32x4 oacc[4];
#pragma unroll
  for (int i = 0; i < 4; ++i) oacc[i] = zero;

  const u16* kgbase = qk + ((size_t)(b * 1024) * 2048 + h * 128 + 64);
  const u16* vgbase = vT + (size_t)bh * 65536;

  for (int kt = 0; kt < 8; ++kt) {
    const int kv0 = kt * 128;
    __syncthreads();
#pragma unroll
    for (int p = 0; p < 2; ++p) {
      int e = p * 512 + tid;
      int kr = e >> 3, kc = e & 7;
      gld_lds16(kgbase + (size_t)(kv0 + kr) * 2048 + ((kc ^ (kr & 7)) * 8),
                &Ks[0][0] + (size_t)(p * 512 + w * 64) * 8);
      int vr = e >> 4, vc = e & 15;
      gld_lds16(vgbase + (size_t)vr * 1024 + kv0 + ((vc ^ (vr & 7)) * 8),
                &Vs[0][0] + (size_t)(p * 512 + w * 64) * 8);
    }
    __syncthreads();

    f32x4 s[8];
    __builtin_amdgcn_s_setprio(1);
#pragma unroll
    for (int jt = 0; jt < 8; ++jt) {
      f32x4 t = zero;
      bf16x8 ak0 = *(const bf16x8*)&Ks[jt * 16 + l15][((l4) ^ (l15 & 7)) * 8];
      bf16x8 ak1 = *(const bf16x8*)&Ks[jt * 16 + l15][((4 + l4) ^ (l15 & 7)) * 8];
      t = mfma16(ak0, bq0, t);
      t = mfma16(ak1, bq1, t);
      s[jt] = t;
    }
    __builtin_amdgcn_s_setprio(0);

    const int ibase = w * 16 + l15 + 1023 - kv0 - l4 * 4;
#pragma unroll
    for (int jt = 0; jt < 8; ++jt)
#pragma unroll
      for (int reg = 0; reg < 4; ++reg)
        s[jt][reg] = s[jt][reg] * (0.125f * 1.44269504f) + rpe_s[ibase - jt * 16 - reg];

    float rm = fmaxf(fmaxf(s[0][0], s[0][1]), fmaxf(s[0][2], s[0][3]));
#pragma unroll
    for (int jt = 1; jt < 8; ++jt)
      rm = fmaxf(rm, fmaxf(fmaxf(s[jt][0], s[jt][1]), fmaxf(s[jt][2], s[jt][3])));
    rm = fmaxf(rm, __shfl_xor(rm, 16));
    rm = fmaxf(rm, __shfl_xor(rm, 32));

    if (__any(rm > m_run)) {
      float mnew = fmaxf(m_run, rm);
      float sc = __builtin_amdgcn_exp2f(m_run - mnew);
      m_run = mnew;
      l_run *= sc;
#pragma unroll
      for (int reg = 0; reg < 4; ++reg) {
        float scr = __shfl(sc, l4 * 4 + reg);
#pragma unroll
        for (int dt = 0; dt < 4; ++dt) oacc[dt][reg] *= scr;
      }
    }

    float rsum = 0.f;
#pragma unroll
    for (int jt = 0; jt < 8; ++jt) {
      float p0 = __builtin_amdgcn_exp2f(s[jt][0] - m_run);
      float p1 = __builtin_amdgcn_exp2f(s[jt][1] - m_run);
      float p2 = __builtin_amdgcn_exp2f(s[jt][2] - m_run);
      float p3 = __builtin_amdgcn_exp2f(s[jt][3] - m_run);
      rsum += (p0 + p1) + (p2 + p3);
      u32 pk01, pk23;
      asm("v_cvt_pk_bf16_f32 %0, %1, %2" : "=v"(pk01) : "v"(p0), "v"(p1));
      asm("v_cvt_pk_bf16_f32 %0, %1, %2" : "=v"(pk23) : "v"(p2), "v"(p3));
      int chunk = (jt * 2 + (l4 >> 1)) ^ (l15 & 7);
      u32* dst = (u32*)&Ps[w][l15][chunk * 8 + (l4 & 1) * 4];
      dst[0] = pk01;
      dst[1] = pk23;
    }
    rsum += __shfl_xor(rsum, 16);
    rsum += __shfl_xor(rsum, 32);
    l_run += rsum;

    __builtin_amdgcn_s_setprio(1);
#pragma unroll
    for (int ksv = 0; ksv < 4; ++ksv) {
      bf16x8 pa = *(const bf16x8*)&Ps[w][l15][((ksv * 4 + l4) ^ (l15 & 7)) * 8];
#pragma unroll
      for (int dt = 0; dt < 4; ++dt) {
        bf16x8 vb = *(const bf16x8*)&Vs[dt * 16 + l15][((ksv * 4 + l4) ^ (l15 & 7)) * 8];
        oacc[dt] = mfma16(pa, vb, oacc[dt]);
      }
    }
    __builtin_amdgcn_s_setprio(0);
  }

  float inv = 1.f / l_run;
#pragma unroll
  for (int reg = 0; reg < 4; ++reg) {
    float invr = __shfl(inv, l4 * 4 + reg);
    int row = b * 1024 + q0 + w * 16 + l4 * 4 + reg;
#pragma unroll
    for (int dt = 0; dt < 4; ++dt)
      attn_out[(size_t)row * 1024 + h * 64 + dt * 16 + l15] = f2bf(oacc[dt][reg] * invr);
  }
}

extern "C" void kernel_launch(void* const* d_in, const int* in_sizes, int n_in,
                              void* d_out, int out_size, void* d_ws, size_t ws_size,
                              hipStream_t stream) {
  const float* x     = (const float*)d_in[0];
  const float* w_qkv = (const float*)d_in[1];
  const float* rpe   = (const float*)d_in[2];
  const float* w_out = (const float*)d_in[3];

  char* ws = (char*)d_ws;
  u16* xb    = (u16*)(ws);                 // [8192][1024]   (16MB)  — aliased:
  u16* attnb = (u16*)(ws);                 // [8192][1024]   (xb dead after G1)
  u16* wqkvT = (u16*)(ws + 16777216);      // [3072][1024]   (6MB)
  u16* woutT = (u16*)(ws + 23068672);      // [1024][1024]   (2MB)  — aliased:
  float* rpeT = (float*)(ws + 23068672);   // [16][2048] f32 (rpeT dead before T2 writes)
  u16* qkbuf = (u16*)(ws + 25165824);      // [8192][2048]   (32MB)
  u16* vTbuf = (u16*)(ws + 58720256);      // [128][64][1024](16MB)

  cast_kernel<<<4096, 256, 0, stream>>>(x, xb, 8192 * 1024 / 8);
  dim3 tb(32, 8);
  transpose_cast_kernel<<<dim3(3072 / 32, 1024 / 32), tb, 0, stream>>>(w_qkv, wqkvT, 1024, 3072);
  rpe_prep_kernel<<<128, 256, 0, stream>>>(rpe, rpeT);

  // G1: M=8192, N=3072, K=1024 -> grid 12x32 = 384 blocks (384 % 8 == 0)
  gemm2_kernel<0><<<384, 512, 0, stream>>>(xb, wqkvT, (void*)qkbuf, (void*)vTbuf,
                                           8192, 3072, 1024, 32);

  attn_kernel<<<1024, 512, 0, stream>>>(qkbuf, vTbuf, rpeT, attnb);

  transpose_cast_kernel<<<dim3(1024 / 32, 1024 / 32), tb, 0, stream>>>(w_out, woutT, 1024, 1024);

  // G3: M=8192, N=1024, K=1024 -> grid 4x32 = 128 blocks (128 % 8 == 0)
  gemm2_kernel<1><<<128, 512, 0, stream>>>(attnb, woutT, d_out, nullptr,
                                           8192, 1024, 1024, 32);
}

// Round 8
// 263.025 us; speedup vs baseline: 1.3683x; 1.0111x over previous
//
#include <hip/hip_runtime.h>

// Pipeline:
//  [C ] xb = bf16(x)                               [8192][1024]
//  [T1] wqkvT = bf16(w_qkv^T)   [P ] rpeT[h][idx] = rpe[idx][h]*log2e
//  [G1] qkv = xb @ w_qkv (256x128 pipelined) -> qk [8192][2048], vT [128][64][1024]
//  [A ] flash attention (+rel-pos bias) -> attnb [8192][1024]  (aliases xb)
//  [T2] woutT = bf16(w_out^T)
//  [G3] out = attnb @ w_out (256x128 pipelined) -> f32 d_out
//
// ws layout (72MB): xb/attnb @0 (16MB) | wqkvT @16MB (6MB) | rpeT/woutT @22MB (2MB)
//                   | qk @24MB (32MB) | vT @56MB (16MB)

typedef __attribute__((ext_vector_type(8))) short bf16x8;
typedef __attribute__((ext_vector_type(4))) float f32x4;
typedef unsigned short u16;
typedef unsigned int u32;

__device__ __forceinline__ u16 f2bf(float f) {
  u32 u = __builtin_bit_cast(u32, f);
  u = (u + 0x7fffu + ((u >> 16) & 1u)) >> 16;
  return (u16)u;
}

__device__ __forceinline__ f32x4 mfma16(bf16x8 a, bf16x8 b, f32x4 c) {
  return __builtin_amdgcn_mfma_f32_16x16x32_bf16(a, b, c, 0, 0, 0);
}

__device__ __forceinline__ void gld_lds16(const u16* g, u16* l) {
  __builtin_amdgcn_global_load_lds(
      (const __attribute__((address_space(1))) unsigned int*)g,
      (__attribute__((address_space(3))) unsigned int*)l, 16, 0, 0);
}

#define BARRIER() asm volatile("s_barrier" ::: "memory")
#define VMCNT2() asm volatile("s_waitcnt vmcnt(2)" ::: "memory")
#define VMCNT0() asm volatile("s_waitcnt vmcnt(0)" ::: "memory")

// ---------------- cast f32 -> bf16, 8 elems/thread ----------------
__global__ __launch_bounds__(256) void cast_kernel(const float* __restrict__ in,
                                                   u16* __restrict__ out, int n8) {
  int i = blockIdx.x * 256 + threadIdx.x;
  if (i >= n8) return;
  float4 a = ((const float4*)in)[2 * i];
  float4 b = ((const float4*)in)[2 * i + 1];
  uint4 o;
  o.x = (u32)f2bf(a.x) | ((u32)f2bf(a.y) << 16);
  o.y = (u32)f2bf(a.z) | ((u32)f2bf(a.w) << 16);
  o.z = (u32)f2bf(b.x) | ((u32)f2bf(b.y) << 16);
  o.w = (u32)f2bf(b.z) | ((u32)f2bf(b.w) << 16);
  ((uint4*)out)[i] = o;
}

// ---------------- transpose + cast: in[R][C] f32 -> out[C][R] bf16 ----------------
__global__ __launch_bounds__(256) void transpose_cast_kernel(const float* __restrict__ in,
                                                             u16* __restrict__ out,
                                                             int R, int C) {
  __shared__ float tile[32][33];
  const int c0 = blockIdx.x * 32, r0 = blockIdx.y * 32;
  const int tx = threadIdx.x, ty = threadIdx.y;  // 32 x 8
#pragma unroll
  for (int i = 0; i < 32; i += 8)
    tile[ty + i][tx] = in[(size_t)(r0 + ty + i) * C + (c0 + tx)];
  __syncthreads();
#pragma unroll
  for (int i = 0; i < 32; i += 8)
    out[(size_t)(c0 + ty + i) * R + (r0 + tx)] = f2bf(tile[tx][ty + i]);
}

// ---------------- rpe transpose prep: rpeT[16][2048] = rpe[i][h]*log2e ----------------
__global__ __launch_bounds__(256) void rpe_prep_kernel(const float* __restrict__ rpe,
                                                       float* __restrict__ rpeT) {
  int o = blockIdx.x * 256 + threadIdx.x;
  int h = o >> 11, i = o & 2047;
  if (i < 2047) rpeT[h * 2048 + i] = rpe[(size_t)i * 16 + h] * 1.44269504f;
}

// ---------------- 256x128 pipelined GEMM: C = A[M][K] @ BT[N][K]^T ----------------
// 512 threads = 8 waves (2M x 4N), per-wave 128x32 out. BK=64, nt=K/64.
// LDS: LA[2][256][64] (64KB) + LB[2][128][64] (32KB) = 96KB, XOR chunk-swizzle.
// 2 phases/tile (M-halves, 16 MFMA each); stage A(t+1) ph1 (4 units), B(t+2) ph2
// (2 units); steady vmcnt(2) (B(t+2) stays in flight). Grid divides 256 evenly:
// G1 768 blocks (3 rounds), G3 256 (1 round) -> no tail.
// EPI 0: qk scatter + vT LDS bounce-transpose (G1).  EPI 1: f32 out (G3).
template <int EPI>
__global__ __launch_bounds__(512, 2) void gemm3_kernel(const u16* __restrict__ A,
                                                       const u16* __restrict__ BT,
                                                       void* __restrict__ C0,
                                                       void* __restrict__ C1,
                                                       int M, int N, int K) {
  __shared__ u16 LA[2][256][64];
  __shared__ u16 LB[2][128][64];
  const int tid = threadIdx.x, lane = tid & 63, w = tid >> 6;
  const int wm = w >> 2, wn = w & 3;
  const int l15 = lane & 15, l4 = lane >> 4;
  const int e7 = l15 & 7;

  // XCD-swizzled 1D grid, by(M)-fastest: same-bx blocks share a B-panel per XCD
  const int nwg = gridDim.x;
  const int virt = ((int)blockIdx.x & 7) * (nwg >> 3) + ((int)blockIdx.x >> 3);
  const int bx = virt >> 5, by = virt & 31;  // M-tiles = 8192/256 = 32
  const int bm0 = by * 256, bn0 = bx * 128;
  const int nt = K >> 6;

  const int sr = tid >> 3, sc = tid & 7;

  auto stageA = [&](int buf, int kt) {
#pragma unroll
    for (int s = 0; s < 4; ++s) {
      int r = s * 64 + sr;
      gld_lds16(A + (size_t)(bm0 + r) * K + kt * 64 + ((sc ^ (r & 7)) * 8),
                &LA[buf][0][0] + s * 4096 + tid * 8);
    }
  };
  auto stageB = [&](int buf, int kt) {
#pragma unroll
    for (int s = 0; s < 2; ++s) {
      int r = s * 64 + sr;
      gld_lds16(BT + (size_t)(bn0 + r) * K + kt * 64 + ((sc ^ (r & 7)) * 8),
                &LB[buf][0][0] + s * 4096 + tid * 8);
    }
  };

  const f32x4 zero = {0.f, 0.f, 0.f, 0.f};
  f32x4 acc[8][2];
#pragma unroll
  for (int i = 0; i < 8; ++i)
#pragma unroll
    for (int j = 0; j < 2; ++j) acc[i][j] = zero;

  bf16x8 afr[8], bfr[4];

  auto ldA = [&](int bt, int mh) {
#pragma unroll
    for (int mi = 0; mi < 4; ++mi)
#pragma unroll
      for (int ks = 0; ks < 2; ++ks)
        afr[mi * 2 + ks] = *(const bf16x8*)&LA[bt][wm * 128 + mh * 64 + mi * 16 + l15]
                                              [((ks * 4 + l4) ^ e7) * 8];
  };
  auto ldB = [&](int bt) {
#pragma unroll
    for (int ni = 0; ni < 2; ++ni)
#pragma unroll
      for (int ks = 0; ks < 2; ++ks)
        bfr[ni * 2 + ks] = *(const bf16x8*)&LB[bt][wn * 32 + ni * 16 + l15]
                                              [((ks * 4 + l4) ^ e7) * 8];
  };
  auto quad = [&](int mh) {
    __builtin_amdgcn_s_setprio(1);
#pragma unroll
    for (int mi = 0; mi < 4; ++mi)
#pragma unroll
      for (int ni = 0; ni < 2; ++ni)
#pragma unroll
        for (int ks = 0; ks < 2; ++ks)
          acc[mh * 4 + mi][ni] =
              mfma16(afr[mi * 2 + ks], bfr[ni * 2 + ks], acc[mh * 4 + mi][ni]);
    __builtin_amdgcn_s_setprio(0);
  };

  // prologue: A(0)+B(0) [6u] + B(1) [2u]; drain tile0 -> vmcnt(2)
  stageA(0, 0);
  stageB(0, 0);
  if (nt > 1) stageB(1, 1);
  VMCNT2();
  BARRIER();

  for (int t = 0; t < nt; ++t) {
    const int bt = t & 1;
    // ph1: read A-half0 + B; stage A(t+1)
    ldA(bt, 0);
    ldB(bt);
    if (t + 1 < nt) stageA(bt ^ 1, t + 1);
    BARRIER();
    quad(0);
    BARRIER();
    // ph2: read A-half1; stage B(t+2); counted drain -> tile t+1 resident
    ldA(bt, 1);
    if (t + 2 < nt) {
      stageB(bt, t + 2);
      VMCNT2();
    } else {
      VMCNT0();
    }
    BARRIER();
    quad(1);
    BARRIER();
  }

  const int rbase = bm0 + wm * 128 + l4 * 4;
  const int cbase = bn0 + wn * 32 + l15;
  if constexpr (EPI == 1) {
    float* C = (float*)C0;
#pragma unroll
    for (int mi = 0; mi < 8; ++mi)
#pragma unroll
      for (int reg = 0; reg < 4; ++reg)
#pragma unroll
        for (int ni = 0; ni < 2; ++ni)
          C[(size_t)(rbase + mi * 16 + reg) * N + cbase + ni * 16] = acc[mi][ni][reg];
  } else {
    u16* qkb = (u16*)C0;
    u16* vT = (u16*)C1;
    const int bq = bm0 >> 10;  // tile never straddles batch (1024 % 256 == 0)
    u16* bbuf = &LA[0][0][0] + w * 2048;  // per-wave 16(n) x 128(m) bounce tile
#pragma unroll
    for (int ni = 0; ni < 2; ++ni) {
      int n16 = bn0 + wn * 32 + ni * 16;  // 16-col run never straddles q/k/v bounds
      int h = n16 / 192, sub = n16 - h * 192;
      if (sub < 128) {
#pragma unroll
        for (int mi = 0; mi < 8; ++mi)
#pragma unroll
          for (int reg = 0; reg < 4; ++reg) {
            int row = rbase + mi * 16 + reg;
            qkb[(size_t)row * 2048 + h * 128 + sub + l15] = f2bf(acc[mi][ni][reg]);
          }
      } else {
        asm volatile("s_waitcnt lgkmcnt(0)" ::: "memory");  // prev ni reads done
#pragma unroll
        for (int mi = 0; mi < 8; ++mi)
#pragma unroll
          for (int reg = 0; reg < 4; ++reg) {
            int ml = mi * 16 + l4 * 4 + reg;  // 0..127
            bbuf[l15 * 128 + (((ml >> 3) ^ e7) * 8) + (ml & 7)] = f2bf(acc[mi][ni][reg]);
          }
        asm volatile("s_waitcnt lgkmcnt(0)" ::: "memory");
        int dsub = sub - 128;
#pragma unroll
        for (int pass = 0; pass < 4; ++pass) {
          int nl = lane >> 2, cc = (lane & 3) + pass * 4;  // cc 0..15
          uint4 val = *(uint4*)&bbuf[nl * 128 + ((cc ^ (nl & 7)) * 8)];
          int mg = bm0 + wm * 128 + cc * 8;
          *(uint4*)&vT[(((size_t)(bq * 16 + h) * 64 + (dsub + nl)) << 10) + (mg & 1023)] =
              val;
        }
      }
    }
  }
}

// ---------------- flash attention with relative position bias ----------------
// qk[8192][2048]: row b*1024+l, cols h*128 + {0..63 q | 64..127 k}
// vT[128 bh][64 d][1024 kv] ; rpeT[16][2048] (pre-scaled by log2e)
// grid 1024: bid = qt*128 + bh (qt 0..7, QBLK=128); same-head blocks share XCD L2.
// 512 threads = 8 waves x 16 q-rows. KVBLK = 128.
// Swapped QK^T: lane owns ONE q-row (q = w*16+l15), kv = jt*16+l4*4+reg.
__global__ __launch_bounds__(512, 4) void attn_kernel(const u16* __restrict__ qk,
                                                      const u16* __restrict__ vT,
                                                      const float* __restrict__ rpeT,
                                                      u16* __restrict__ attn_out) {
  __shared__ u16 Ks[128][64];     // K tile [kv][d], chunk c holds global chunk c^(kv&7)
  __shared__ u16 Vs[64][128];     // V^T    [d][kv], chunk c holds global chunk c^(d&7)
  __shared__ u16 Ps[8][16][128];  // per-wave P [q][kv], chunk ^= q&7
  __shared__ float rpe_s[1152];   // rpeT[h][q0 .. q0+1150]

  const int tid = threadIdx.x, lane = tid & 63, w = tid >> 6;
  const int l15 = lane & 15, l4 = lane >> 4;
  const int bid = blockIdx.x;
  const int qt = bid >> 7, bh = bid & 127;
  const int h = bh & 15, b = bh >> 4;
  const int q0 = qt * 128;

  for (int t = tid; t < 1151; t += 512)
    rpe_s[t] = rpeT[h * 2048 + q0 + t];

  const u16* qbase = qk + ((size_t)(b * 1024 + q0 + w * 16 + l15) * 2048 + h * 128);
  bf16x8 bq0 = *(const bf16x8*)(qbase + l4 * 8);
  bf16x8 bq1 = *(const bf16x8*)(qbase + 32 + l4 * 8);

  const f32x4 zero = {0.f, 0.f, 0.f, 0.f};
  float m_run = -1e30f, l_run = 0.f;
  f32x4 oacc[4];
#pragma unroll
  for (int i = 0; i < 4; ++i) oacc[i] = zero;

  const u16* kgbase = qk + ((size_t)(b * 1024) * 2048 + h * 128 + 64);
  const u16* vgbase = vT + (size_t)bh * 65536;

  for (int kt = 0; kt < 8; ++kt) {
    const int kv0 = kt * 128;
    __syncthreads();
#pragma unroll
    for (int p = 0; p < 2; ++p) {
      int e = p * 512 + tid;
      int kr = e >> 3, kc = e & 7;
      gld_lds16(kgbase + (size_t)(kv0 + kr) * 2048 + ((kc ^ (kr & 7)) * 8),
                &Ks[0][0] + (size_t)(p * 512 + w * 64) * 8);
      int vr = e >> 4, vc = e & 15;
      gld_lds16(vgbase + (size_t)vr * 1024 + kv0 + ((vc ^ (vr & 7)) * 8),
                &Vs[0][0] + (size_t)(p * 512 + w * 64) * 8);
    }
    __syncthreads();

    f32x4 s[8];
    __builtin_amdgcn_s_setprio(1);
#pragma unroll
    for (int jt = 0; jt < 8; ++jt) {
      f32x4 t = zero;
      bf16x8 ak0 = *(const bf16x8*)&Ks[jt * 16 + l15][((l4) ^ (l15 & 7)) * 8];
      bf16x8 ak1 = *(const bf16x8*)&Ks[jt * 16 + l15][((4 + l4) ^ (l15 & 7)) * 8];
      t = mfma16(ak0, bq0, t);
      t = mfma16(ak1, bq1, t);
      s[jt] = t;
    }
    __builtin_amdgcn_s_setprio(0);

    const int ibase = w * 16 + l15 + 1023 - kv0 - l4 * 4;
#pragma unroll
    for (int jt = 0; jt < 8; ++jt)
#pragma unroll
      for (int reg = 0; reg < 4; ++reg)
        s[jt][reg] = s[jt][reg] * (0.125f * 1.44269504f) + rpe_s[ibase - jt * 16 - reg];

    float rm = fmaxf(fmaxf(s[0][0], s[0][1]), fmaxf(s[0][2], s[0][3]));
#pragma unroll
    for (int jt = 1; jt < 8; ++jt)
      rm = fmaxf(rm, fmaxf(fmaxf(s[jt][0], s[jt][1]), fmaxf(s[jt][2], s[jt][3])));
    rm = fmaxf(rm, __shfl_xor(rm, 16));
    rm = fmaxf(rm, __shfl_xor(rm, 32));

    if (__any(rm > m_run)) {
      float mnew = fmaxf(m_run, rm);
      float sc = __builtin_amdgcn_exp2f(m_run - mnew);
      m_run = mnew;
      l_run *= sc;
#pragma unroll
      for (int reg = 0; reg < 4; ++reg) {
        float scr = __shfl(sc, l4 * 4 + reg);
#pragma unroll
        for (int dt = 0; dt < 4; ++dt) oacc[dt][reg] *= scr;
      }
    }

    float rsum = 0.f;
#pragma unroll
    for (int jt = 0; jt < 8; ++jt) {
      float p0 = __builtin_amdgcn_exp2f(s[jt][0] - m_run);
      float p1 = __builtin_amdgcn_exp2f(s[jt][1] - m_run);
      float p2 = __builtin_amdgcn_exp2f(s[jt][2] - m_run);
      float p3 = __builtin_amdgcn_exp2f(s[jt][3] - m_run);
      rsum += (p0 + p1) + (p2 + p3);
      u32 pk01, pk23;
      asm("v_cvt_pk_bf16_f32 %0, %1, %2" : "=v"(pk01) : "v"(p0), "v"(p1));
      asm("v_cvt_pk_bf16_f32 %0, %1, %2" : "=v"(pk23) : "v"(p2), "v"(p3));
      int chunk = (jt * 2 + (l4 >> 1)) ^ (l15 & 7);
      u32* dst = (u32*)&Ps[w][l15][chunk * 8 + (l4 & 1) * 4];
      dst[0] = pk01;
      dst[1] = pk23;
    }
    rsum += __shfl_xor(rsum, 16);
    rsum += __shfl_xor(rsum, 32);
    l_run += rsum;

    __builtin_amdgcn_s_setprio(1);
#pragma unroll
    for (int ksv = 0; ksv < 4; ++ksv) {
      bf16x8 pa = *(const bf16x8*)&Ps[w][l15][((ksv * 4 + l4) ^ (l15 & 7)) * 8];
#pragma unroll
      for (int dt = 0; dt < 4; ++dt) {
        bf16x8 vb = *(const bf16x8*)&Vs[dt * 16 + l15][((ksv * 4 + l4) ^ (l15 & 7)) * 8];
        oacc[dt] = mfma16(pa, vb, oacc[dt]);
      }
    }
    __builtin_amdgcn_s_setprio(0);
  }

  float inv = 1.f / l_run;
#pragma unroll
  for (int reg = 0; reg < 4; ++reg) {
    float invr = __shfl(inv, l4 * 4 + reg);
    int row = b * 1024 + q0 + w * 16 + l4 * 4 + reg;
#pragma unroll
    for (int dt = 0; dt < 4; ++dt)
      attn_out[(size_t)row * 1024 + h * 64 + dt * 16 + l15] = f2bf(oacc[dt][reg] * invr);
  }
}

extern "C" void kernel_launch(void* const* d_in, const int* in_sizes, int n_in,
                              void* d_out, int out_size, void* d_ws, size_t ws_size,
                              hipStream_t stream) {
  const float* x     = (const float*)d_in[0];
  const float* w_qkv = (const float*)d_in[1];
  const float* rpe   = (const float*)d_in[2];
  const float* w_out = (const float*)d_in[3];

  char* ws = (char*)d_ws;
  u16* xb    = (u16*)(ws);                 // [8192][1024]   (16MB)  — aliased:
  u16* attnb = (u16*)(ws);                 // [8192][1024]   (xb dead after G1)
  u16* wqkvT = (u16*)(ws + 16777216);      // [3072][1024]   (6MB)
  u16* woutT = (u16*)(ws + 23068672);      // [1024][1024]   (2MB)  — aliased:
  float* rpeT = (float*)(ws + 23068672);   // [16][2048] f32 (rpeT dead before T2 writes)
  u16* qkbuf = (u16*)(ws + 25165824);      // [8192][2048]   (32MB)
  u16* vTbuf = (u16*)(ws + 58720256);      // [128][64][1024](16MB)

  cast_kernel<<<4096, 256, 0, stream>>>(x, xb, 8192 * 1024 / 8);
  dim3 tb(32, 8);
  transpose_cast_kernel<<<dim3(3072 / 32, 1024 / 32), tb, 0, stream>>>(w_qkv, wqkvT, 1024, 3072);
  rpe_prep_kernel<<<128, 256, 0, stream>>>(rpe, rpeT);

  // G1: 32 M-tiles x 24 N-tiles = 768 blocks (3 even rounds on 256 CUs)
  gemm3_kernel<0><<<768, 512, 0, stream>>>(xb, wqkvT, (void*)qkbuf, (void*)vTbuf,
                                           8192, 3072, 1024);

  attn_kernel<<<1024, 512, 0, stream>>>(qkbuf, vTbuf, rpeT, attnb);

  transpose_cast_kernel<<<dim3(1024 / 32, 1024 / 32), tb, 0, stream>>>(w_out, woutT, 1024, 1024);

  // G3: 32 M-tiles x 8 N-tiles = 256 blocks (1 full round)
  gemm3_kernel<1><<<256, 512, 0, stream>>>(attnb, woutT, d_out, nullptr,
                                           8192, 1024, 1024);
}